// Round 2
// baseline (1612.252 us; speedup 1.0000x reference)
//
#include <hip/hip_runtime.h>
#include <hip/hip_bf16.h>

#define NN 100000
#define EE 1600000
#define NB 98      // ceil(NN/1024)
#define NBIN 64

__device__ __forceinline__ float act_apply(float v, int act) {
  if (act == 1) return 1.0f / (1.0f + expf(-v));
  if (act == 2) return fmaxf(v, 0.0f);
  return v;
}
__device__ __forceinline__ float4 act4(float4 v, int act) {
  v.x = act_apply(v.x, act); v.y = act_apply(v.y, act);
  v.z = act_apply(v.z, act); v.w = act_apply(v.w, act);
  return v;
}
__device__ __forceinline__ float4 f4fma(float s, float4 v, float4 a) {
  a.x += s * v.x; a.y += s * v.y; a.z += s * v.z; a.w += s * v.w; return a;
}
__device__ __forceinline__ float4 f4add(float4 a, float4 b) {
  a.x += b.x; a.y += b.y; a.z += b.z; a.w += b.w; return a;
}
__device__ __forceinline__ float4 f4scale(float4 a, float s) {
  a.x *= s; a.y *= s; a.z *= s; a.w *= s; return a;
}

// ---------------- CSR build ----------------
__global__ void k_count(const int* __restrict__ ei, int* __restrict__ cnt) {
  int e = blockIdx.x * blockDim.x + threadIdx.x;
  if (e < EE) atomicAdd(&cnt[ei[EE + e]], 1);
}

__global__ __launch_bounds__(1024) void k_bsum(const int* __restrict__ cnt, int* __restrict__ bsum) {
  int i = blockIdx.x * 1024 + threadIdx.x;
  int v = (i < NN) ? cnt[i] : 0;
  for (int d = 1; d < 64; d <<= 1) v += __shfl_xor(v, d, 64);
  __shared__ int ws[16];
  int lane = threadIdx.x & 63, wid = threadIdx.x >> 6;
  if (lane == 0) ws[wid] = v;
  __syncthreads();
  if (threadIdx.x == 0) {
    int s = 0;
    for (int j = 0; j < 16; ++j) s += ws[j];
    bsum[blockIdx.x] = s;
  }
}

__global__ void k_bscan(const int* __restrict__ bsum, int* __restrict__ bexcl) {
  __shared__ int sh[128];
  int tid = threadIdx.x;
  int v = (tid < NB) ? bsum[tid] : 0;
  sh[tid] = v;
  __syncthreads();
  for (int d = 1; d < 128; d <<= 1) {
    int t = (tid >= d) ? sh[tid - d] : 0;
    __syncthreads();
    sh[tid] += t;
    __syncthreads();
  }
  if (tid < NB) bexcl[tid] = sh[tid] - v;
}

__global__ __launch_bounds__(1024) void k_bapply(const int* __restrict__ cnt,
                                                 const int* __restrict__ bexcl,
                                                 int* __restrict__ off, int* __restrict__ cursor,
                                                 float* __restrict__ dis) {
  int i = blockIdx.x * 1024 + threadIdx.x;
  int v = (i < NN) ? cnt[i] : 0;
  int lane = threadIdx.x & 63, wid = threadIdx.x >> 6;
  int incl = v;
  for (int d = 1; d < 64; d <<= 1) {
    int t = __shfl_up(incl, d, 64);
    if (lane >= d) incl += t;
  }
  __shared__ int ws[16];
  if (lane == 63) ws[wid] = incl;
  __syncthreads();
  if (threadIdx.x == 0) {
    int run = 0;
    for (int j = 0; j < 16; ++j) { int t = ws[j]; ws[j] = run; run += t; }
  }
  __syncthreads();
  int ex = incl - v + ws[wid] + bexcl[blockIdx.x];
  if (i < NN) {
    off[i] = ex;
    cursor[i] = ex;
    dis[i] = (v > 0) ? rsqrtf((float)v) : 0.0f;
  }
  if (blockIdx.x == 0 && threadIdx.x == 0) off[NN] = EE;
}

__global__ void k_fill(const int* __restrict__ ei, int* __restrict__ cursor,
                       int* __restrict__ csr_src) {
  int e = blockIdx.x * blockDim.x + threadIdx.x;
  if (e < EE) {
    int d = ei[EE + e];
    int pos = atomicAdd(&cursor[d], 1);
    csr_src[pos] = ei[e];
  }
}

// ---------------- degree sort (perm) ----------------
__global__ void k_hist(const int* __restrict__ cnt, int* __restrict__ hist) {
  int i = blockIdx.x * blockDim.x + threadIdx.x;
  if (i < NN) atomicAdd(&hist[min(cnt[i], NBIN - 1)], 1);
}
__global__ void k_binscan(const int* __restrict__ hist, int* __restrict__ bincur) {
  int tid = threadIdx.x;
  int v = hist[tid];
  int incl = v;
  for (int d = 1; d < 64; d <<= 1) {
    int t = __shfl_up(incl, d, 64);
    if (tid >= d) incl += t;
  }
  bincur[tid] = incl - v;
}
__global__ void k_scatter(const int* __restrict__ cnt, int* __restrict__ bincur,
                          int* __restrict__ perm) {
  int i = blockIdx.x * blockDim.x + threadIdx.x;
  if (i < NN) {
    int b = min(cnt[i], NBIN - 1);
    int pos = atomicAdd(&bincur[b], 1);
    perm[pos] = i;
  }
}

// ---------------- pad x [N,11] -> [N,12] ----------------
__global__ void k_pad12(const float* __restrict__ x, float* __restrict__ x12) {
  int i = blockIdx.x * blockDim.x + threadIdx.x;
  if (i >= NN * 12) return;
  int n = i / 12, j = i - n * 12;
  x12[i] = (j < 11) ? x[n * 11 + j] : 0.0f;
}

// ---------------- gathers ----------------
// mean over neighbors, D=12 (padded), G=4 (t<3 active), float4
__global__ void k_gmean12(const float* __restrict__ x12, const int* __restrict__ perm,
                          const int* __restrict__ off, const int* __restrict__ srcarr,
                          float* __restrict__ out) {
  int g = blockIdx.x * 64 + (threadIdx.x >> 2);
  int t = threadIdx.x & 3;
  if (g >= NN || t >= 3) return;
  int node = perm[g];
  int s = off[node], e = off[node + 1];
  const float4* h4 = (const float4*)x12;
  float4 acc = {0, 0, 0, 0};
  int p = s;
  for (; p + 4 <= e; p += 4) {
    int s0 = srcarr[p], s1 = srcarr[p + 1], s2 = srcarr[p + 2], s3 = srcarr[p + 3];
    float4 v0 = h4[(long)s0 * 3 + t], v1 = h4[(long)s1 * 3 + t];
    float4 v2 = h4[(long)s2 * 3 + t], v3 = h4[(long)s3 * 3 + t];
    acc = f4add(acc, f4add(f4add(v0, v1), f4add(v2, v3)));
  }
  for (; p < e; ++p) {
    int s0 = srcarr[p];
    acc = f4add(acc, h4[(long)s0 * 3 + t]);
  }
  int c = e - s;
  float inv = 1.0f / (float)(c > 0 ? c : 1);
  ((float4*)out)[(long)node * 3 + t] = f4scale(acc, inv);
}

// mean over neighbors, D=128, G=32, float4, unroll 4
__global__ void k_gather128(const float* __restrict__ h, const int* __restrict__ perm,
                            const int* __restrict__ off, const int* __restrict__ srcarr,
                            float* __restrict__ out) {
  int g = blockIdx.x * 8 + (threadIdx.x >> 5);
  int t = threadIdx.x & 31;
  if (g >= NN) return;
  int node = perm[g];
  int s = off[node], e = off[node + 1];
  const float4* h4 = (const float4*)h;
  float4 acc = {0, 0, 0, 0};
  int p = s;
  for (; p + 4 <= e; p += 4) {
    int s0 = srcarr[p], s1 = srcarr[p + 1], s2 = srcarr[p + 2], s3 = srcarr[p + 3];
    float4 v0 = h4[(long)s0 * 32 + t], v1 = h4[(long)s1 * 32 + t];
    float4 v2 = h4[(long)s2 * 32 + t], v3 = h4[(long)s3 * 32 + t];
    acc = f4add(acc, f4add(f4add(v0, v1), f4add(v2, v3)));
  }
  for (; p < e; ++p) {
    int s0 = srcarr[p];
    acc = f4add(acc, h4[(long)s0 * 32 + t]);
  }
  int c = e - s;
  float inv = 1.0f / (float)(c > 0 ? c : 1);
  ((float4*)out)[(long)node * 32 + t] = f4scale(acc, inv);
}

// TAG-norm D=8 gather, dual streams (two independent chains share edges)
__global__ void k_g8_dual(
    const float* __restrict__ ha, int hsa4, const float* __restrict__ adda, int asa4,
    const float* __restrict__ biasa, int acta,
    const float* __restrict__ hb, int hsb4, const float* __restrict__ addb, int asb4,
    const float* __restrict__ biasb, int actb,
    const int* __restrict__ perm, const int* __restrict__ off,
    const int* __restrict__ srcarr, const float* __restrict__ dis,
    float* __restrict__ outa, int osa4, float* __restrict__ outb, int osb4) {
  int g = blockIdx.x * 128 + (threadIdx.x >> 1);
  int t = threadIdx.x & 1;
  if (g >= NN) return;
  int node = perm[g];
  int s = off[node], e = off[node + 1];
  const float4* ha4 = (const float4*)ha;
  const float4* hb4 = (const float4*)hb;
  float4 accA = {0, 0, 0, 0}, accB = {0, 0, 0, 0};
  int p = s;
  for (; p + 2 <= e; p += 2) {
    int s0 = srcarr[p], s1 = srcarr[p + 1];
    float d0 = dis[s0], d1 = dis[s1];
    float4 a0 = ha4[(long)s0 * hsa4 + t], a1 = ha4[(long)s1 * hsa4 + t];
    float4 b0 = hb4[(long)s0 * hsb4 + t], b1 = hb4[(long)s1 * hsb4 + t];
    accA = f4fma(d0, a0, accA); accA = f4fma(d1, a1, accA);
    accB = f4fma(d0, b0, accB); accB = f4fma(d1, b1, accB);
  }
  if (p < e) {
    int s0 = srcarr[p];
    float d0 = dis[s0];
    accA = f4fma(d0, ha4[(long)s0 * hsa4 + t], accA);
    accB = f4fma(d0, hb4[(long)s0 * hsb4 + t], accB);
  }
  float dn = dis[node];
  float4 rA = f4scale(accA, dn);
  rA = f4add(rA, ((const float4*)adda)[(long)node * asa4 + t]);
  if (biasa) rA = f4add(rA, ((const float4*)biasa)[t]);
  ((float4*)outa)[(long)node * osa4 + t] = act4(rA, acta);
  float4 rB = f4scale(accB, dn);
  rB = f4add(rB, ((const float4*)addb)[(long)node * asb4 + t]);
  if (biasb) rB = f4add(rB, ((const float4*)biasb)[t]);
  ((float4*)outb)[(long)node * osb4 + t] = act4(rB, actb);
}

__global__ void k_g8_single(
    const float* __restrict__ ha, int hsa4, const float* __restrict__ adda, int asa4,
    const float* __restrict__ biasa, int acta,
    const int* __restrict__ perm, const int* __restrict__ off,
    const int* __restrict__ srcarr, const float* __restrict__ dis,
    float* __restrict__ outa, int osa4) {
  int g = blockIdx.x * 128 + (threadIdx.x >> 1);
  int t = threadIdx.x & 1;
  if (g >= NN) return;
  int node = perm[g];
  int s = off[node], e = off[node + 1];
  const float4* ha4 = (const float4*)ha;
  float4 accA = {0, 0, 0, 0};
  int p = s;
  for (; p + 4 <= e; p += 4) {
    int s0 = srcarr[p], s1 = srcarr[p + 1], s2 = srcarr[p + 2], s3 = srcarr[p + 3];
    float d0 = dis[s0], d1 = dis[s1], d2 = dis[s2], d3 = dis[s3];
    accA = f4fma(d0, ha4[(long)s0 * hsa4 + t], accA);
    accA = f4fma(d1, ha4[(long)s1 * hsa4 + t], accA);
    accA = f4fma(d2, ha4[(long)s2 * hsa4 + t], accA);
    accA = f4fma(d3, ha4[(long)s3 * hsa4 + t], accA);
  }
  for (; p < e; ++p) {
    int s0 = srcarr[p];
    accA = f4fma(dis[s0], ha4[(long)s0 * hsa4 + t], accA);
  }
  float4 rA = f4scale(accA, dis[node]);
  rA = f4add(rA, ((const float4*)adda)[(long)node * asa4 + t]);
  if (biasa) rA = f4add(rA, ((const float4*)biasa)[t]);
  ((float4*)outa)[(long)node * osa4 + t] = act4(rA, acta);
}

// 1-dim gathers: G=4 lanes per node, shuffle reduce. MODE 0 = SAGE mean, 1 = TAG norm.
template<int MODE>
__global__ void k_g1_dual(
    const float* __restrict__ ua, int hsa, const float* __restrict__ adda, int asa,
    const float* __restrict__ biasa, int acta,
    const float* __restrict__ ub, int hsb, const float* __restrict__ addb, int asb,
    const float* __restrict__ biasb, int actb,
    const int* __restrict__ perm, const int* __restrict__ off,
    const int* __restrict__ srcarr, const float* __restrict__ dis,
    float* __restrict__ outa, float* __restrict__ outb) {
  int g = blockIdx.x * 64 + (threadIdx.x >> 2);
  int t = threadIdx.x & 3;
  if (g >= NN) return;
  int node = perm[g];
  int s = off[node], e = off[node + 1];
  float accA = 0.0f, accB = 0.0f;
  for (int p = s + t; p < e; p += 4) {
    int s0 = srcarr[p];
    float d = (MODE == 1) ? dis[s0] : 1.0f;
    accA += d * ua[(long)s0 * hsa];
    accB += d * ub[(long)s0 * hsb];
  }
  accA += __shfl_xor(accA, 1, 64); accA += __shfl_xor(accA, 2, 64);
  accB += __shfl_xor(accB, 1, 64); accB += __shfl_xor(accB, 2, 64);
  if (t == 0) {
    float sc;
    if (MODE == 0) { int c = e - s; sc = 1.0f / (float)(c > 0 ? c : 1); }
    else sc = dis[node];
    float rA = accA * sc + adda[(long)node * asa];
    if (biasa) rA += biasa[0];
    outa[node] = act_apply(rA, acta);
    float rB = accB * sc + addb[(long)node * asb];
    if (biasb) rB += biasb[0];
    outb[node] = act_apply(rB, actb);
  }
}

template<int MODE>
__global__ void k_g1_single(
    const float* __restrict__ ua, int hsa, const float* __restrict__ adda, int asa,
    const float* __restrict__ biasa, int acta,
    const int* __restrict__ perm, const int* __restrict__ off,
    const int* __restrict__ srcarr, const float* __restrict__ dis,
    float* __restrict__ outa) {
  int g = blockIdx.x * 64 + (threadIdx.x >> 2);
  int t = threadIdx.x & 3;
  if (g >= NN) return;
  int node = perm[g];
  int s = off[node], e = off[node + 1];
  float accA = 0.0f;
  for (int p = s + t; p < e; p += 4) {
    int s0 = srcarr[p];
    float d = (MODE == 1) ? dis[s0] : 1.0f;
    accA += d * ua[(long)s0 * hsa];
  }
  accA += __shfl_xor(accA, 1, 64); accA += __shfl_xor(accA, 2, 64);
  if (t == 0) {
    float sc;
    if (MODE == 0) { int c = e - s; sc = 1.0f / (float)(c > 0 ? c : 1); }
    else sc = dis[node];
    float rA = accA * sc + adda[(long)node * asa];
    if (biasa) rA += biasa[0];
    outa[node] = act_apply(rA, acta);
  }
}

// ---------------- SAGE layer-1 fused GEMM (small K) ----------------
template<int K1, int K2>
__global__ __launch_bounds__(256) void k_sage_mm(
    const float* __restrict__ A1, int as1, const float* __restrict__ A2, int as2,
    const float* __restrict__ W1, const float* __restrict__ W2,
    const float* __restrict__ bias, float* __restrict__ out, int act) {
  constexpr int K = K1 + K2;
  constexpr int BM = 64;
  constexpr int BK = 32;
  __shared__ float Ash[BK][BM];
  __shared__ float Wsh[BK][128];
  int m0 = blockIdx.x * BM;
  int tid = threadIdx.x;
  int tx = tid & 15, ty = tid >> 4;
  int tm = ty * 4;
  int to = tx * 8;
  float acc[4][8] = {};
  for (int k0 = 0; k0 < K; k0 += BK) {
    {
      int mm = tid % BM, kb = tid / BM;
      #pragma unroll
      for (int it = 0; it < BK / 4; ++it) {
        int kk = kb + 4 * it;
        int gk = k0 + kk, gm = m0 + mm;
        float v = 0.0f;
        if (gm < NN && gk < K)
          v = (gk < K1) ? A1[(long)gm * as1 + gk] : A2[(long)gm * as2 + (gk - K1)];
        Ash[kk][mm] = v;
      }
    }
    {
      int oo = tid % 128, kb = tid / 128;
      #pragma unroll
      for (int it = 0; it < BK / 2; ++it) {
        int kk = kb + 2 * it;
        int gk = k0 + kk;
        float v = 0.0f;
        if (gk < K)
          v = (gk < K1) ? W1[oo * K1 + gk] : W2[oo * K2 + (gk - K1)];
        Wsh[kk][oo] = v;
      }
    }
    __syncthreads();
    #pragma unroll
    for (int kk = 0; kk < BK; ++kk) {
      float4 av = *reinterpret_cast<const float4*>(&Ash[kk][tm]);
      float4 wv0 = *reinterpret_cast<const float4*>(&Wsh[kk][to]);
      float4 wv1 = *reinterpret_cast<const float4*>(&Wsh[kk][to + 4]);
      float a[4] = {av.x, av.y, av.z, av.w};
      float w[8] = {wv0.x, wv0.y, wv0.z, wv0.w, wv1.x, wv1.y, wv1.z, wv1.w};
      #pragma unroll
      for (int i2 = 0; i2 < 4; ++i2)
        #pragma unroll
        for (int j = 0; j < 8; ++j)
          acc[i2][j] += a[i2] * w[j];
    }
    __syncthreads();
  }
  #pragma unroll
  for (int i2 = 0; i2 < 4; ++i2) {
    int gm = m0 + tm + i2;
    if (gm >= NN) continue;
    float4 o0, o1;
    o0.x = act_apply(acc[i2][0] + bias[to + 0], act);
    o0.y = act_apply(acc[i2][1] + bias[to + 1], act);
    o0.z = act_apply(acc[i2][2] + bias[to + 2], act);
    o0.w = act_apply(acc[i2][3] + bias[to + 3], act);
    o1.x = act_apply(acc[i2][4] + bias[to + 4], act);
    o1.y = act_apply(acc[i2][5] + bias[to + 5], act);
    o1.z = act_apply(acc[i2][6] + bias[to + 6], act);
    o1.w = act_apply(acc[i2][7] + bias[to + 7], act);
    *reinterpret_cast<float4*>(&out[(long)gm * 128 + to]) = o0;
    *reinterpret_cast<float4*>(&out[(long)gm * 128 + to + 4]) = o1;
  }
}

// ---------------- SAGE layer-2 GEMM: 128x128 tile, BK=16, 8x8/thread ----------------
__global__ __launch_bounds__(256) void k_mm2(
    const float* __restrict__ A1, const float* __restrict__ A2,
    const float* __restrict__ W1, const float* __restrict__ W2,
    const float* __restrict__ bias, float* __restrict__ out, int act) {
  __shared__ float Ash[16][132];
  __shared__ float Wsh[16][132];
  int tid = threadIdx.x;
  int m0 = blockIdx.x * 128;
  int r = tid >> 2;
  int c = tid & 3;
  int tx = tid & 15, ty = tid >> 4;
  int tm = ty * 8;
  int to = tx * 4;
  float acc[8][8] = {};
  for (int k0 = 0; k0 < 256; k0 += 16) {
    const float* Asrc;
    const float* Wsrc;
    int kk0;
    if (k0 < 128) { Asrc = A1; Wsrc = W1; kk0 = k0; }
    else { Asrc = A2; Wsrc = W2; kk0 = k0 - 128; }
    #pragma unroll
    for (int h = 0; h < 2; ++h) {
      int row = r + h * 64;
      int gm = m0 + row;
      float4 v = {0, 0, 0, 0};
      if (gm < NN) v = *(const float4*)&Asrc[(long)gm * 128 + kk0 + c * 4];
      Ash[c * 4 + 0][row] = v.x; Ash[c * 4 + 1][row] = v.y;
      Ash[c * 4 + 2][row] = v.z; Ash[c * 4 + 3][row] = v.w;
    }
    #pragma unroll
    for (int h = 0; h < 2; ++h) {
      int oo = r + h * 64;
      float4 v = *(const float4*)&Wsrc[oo * 128 + kk0 + c * 4];
      Wsh[c * 4 + 0][oo] = v.x; Wsh[c * 4 + 1][oo] = v.y;
      Wsh[c * 4 + 2][oo] = v.z; Wsh[c * 4 + 3][oo] = v.w;
    }
    __syncthreads();
    #pragma unroll
    for (int kk = 0; kk < 16; ++kk) {
      float a[8], w[8];
      *(float4*)&a[0] = *(const float4*)&Ash[kk][tm];
      *(float4*)&a[4] = *(const float4*)&Ash[kk][tm + 4];
      *(float4*)&w[0] = *(const float4*)&Wsh[kk][to];
      *(float4*)&w[4] = *(const float4*)&Wsh[kk][to + 64];
      #pragma unroll
      for (int i = 0; i < 8; ++i)
        #pragma unroll
        for (int j = 0; j < 8; ++j)
          acc[i][j] += a[i] * w[j];
    }
    __syncthreads();
  }
  #pragma unroll
  for (int i = 0; i < 8; ++i) {
    int gm = m0 + tm + i;
    if (gm >= NN) continue;
    float4 o0, o1;
    o0.x = act_apply(acc[i][0] + bias[to + 0], act);
    o0.y = act_apply(acc[i][1] + bias[to + 1], act);
    o0.z = act_apply(acc[i][2] + bias[to + 2], act);
    o0.w = act_apply(acc[i][3] + bias[to + 3], act);
    o1.x = act_apply(acc[i][4] + bias[to + 64], act);
    o1.y = act_apply(acc[i][5] + bias[to + 65], act);
    o1.z = act_apply(acc[i][6] + bias[to + 66], act);
    o1.w = act_apply(acc[i][7] + bias[to + 67], act);
    *(float4*)&out[(long)gm * 128 + to] = o0;
    *(float4*)&out[(long)gm * 128 + to + 64] = o1;
  }
}

// ---------------- TAG P-precompute ----------------
template<int KIN, int NH, int NO>
__global__ void k_tagP(const float* __restrict__ A, int as,
                       const float* __restrict__ w, float* __restrict__ out, int os) {
  int i = blockIdx.x * blockDim.x + threadIdx.x;
  if (i >= NN) return;
  float a[KIN];
  #pragma unroll
  for (int j = 0; j < KIN; ++j) a[j] = A[(long)i * as + j];
  #pragma unroll
  for (int k = 0; k < NH; ++k) {
    #pragma unroll
    for (int o = 0; o < NO; ++o) {
      float s = 0.0f;
      #pragma unroll
      for (int j = 0; j < KIN; ++j) s += a[j] * w[o * (KIN * NH) + k * KIN + j];
      out[(long)i * os + k * NO + o] = s;
    }
  }
}

__global__ void k_proj2(const float* __restrict__ A, const float* __restrict__ w1,
                        const float* __restrict__ w2, float* __restrict__ P,
                        float* __restrict__ Q) {
  int i = blockIdx.x * blockDim.x + threadIdx.x;
  if (i >= NN) return;
  const float4* a4 = reinterpret_cast<const float4*>(A + (long)i * 128);
  float s1 = 0.0f, s2 = 0.0f;
  #pragma unroll
  for (int k = 0; k < 32; ++k) {
    float4 v = a4[k];
    s1 += v.x * w1[4 * k] + v.y * w1[4 * k + 1] + v.z * w1[4 * k + 2] + v.w * w1[4 * k + 3];
    s2 += v.x * w2[4 * k] + v.y * w2[4 * k + 1] + v.z * w2[4 * k + 2] + v.w * w2[4 * k + 3];
  }
  P[i] = s1;
  Q[i] = s2;
}

__global__ void k_final(const float* __restrict__ x1, const float* __restrict__ x2,
                        const float* __restrict__ x3, const float* __restrict__ lw,
                        const float* __restrict__ lb, float* __restrict__ out) {
  int i = blockIdx.x * blockDim.x + threadIdx.x;
  if (i >= NN) return;
  float v = x1[i] * lw[0] + x2[i] * lw[1] + x3[i] * lw[2] + lb[0];
  out[i] = fmaxf(v, 0.0f);
}

extern "C" void kernel_launch(void* const* d_in, const int* in_sizes, int n_in,
                              void* d_out, int out_size, void* d_ws, size_t ws_size,
                              hipStream_t stream) {
  const float* x    = (const float*)d_in[0];
  const int*   ei   = (const int*)d_in[1];
  const float* s1wl = (const float*)d_in[2];
  const float* s1wr = (const float*)d_in[3];
  const float* s1b  = (const float*)d_in[4];
  const float* s2wl = (const float*)d_in[5];
  const float* s2wr = (const float*)d_in[6];
  const float* s2b  = (const float*)d_in[7];
  const float* s3wl = (const float*)d_in[8];
  const float* s3wr = (const float*)d_in[9];
  const float* s3b  = (const float*)d_in[10];
  const float* t1aw = (const float*)d_in[11];
  const float* t1ab = (const float*)d_in[12];
  const float* t2aw = (const float*)d_in[13];
  const float* t2ab = (const float*)d_in[14];
  const float* t1bw = (const float*)d_in[15];
  const float* t1bb = (const float*)d_in[16];
  const float* t2bw = (const float*)d_in[17];
  const float* t2bb = (const float*)d_in[18];
  const float* lw   = (const float*)d_in[19];
  const float* lb   = (const float*)d_in[20];
  float* out = (float*)d_out;

  char* basep = (char*)d_ws;
  size_t off = 0;
  auto alloc = [&](size_t bytes) -> void* {
    void* ptr = basep + off;
    off = (off + bytes + 255) & ~(size_t)255;
    return ptr;
  };
  int*   cnt     = (int*)alloc((size_t)NN * 4);
  int*   csr_off = (int*)alloc((size_t)(NN + 1) * 4);
  int*   cursor  = (int*)alloc((size_t)NN * 4);
  float* dis     = (float*)alloc((size_t)NN * 4);
  int*   csr_src = (int*)alloc((size_t)EE * 4);
  int*   perm    = (int*)alloc((size_t)NN * 4);
  int*   bsum    = (int*)alloc(128 * 4);
  int*   bexcl   = (int*)alloc(128 * 4);
  int*   hist    = (int*)alloc(NBIN * 4);
  int*   bincur  = (int*)alloc(NBIN * 4);
  float* x1s     = (float*)alloc((size_t)NN * 4);
  float* x2s     = (float*)alloc((size_t)NN * 4);
  float* x3s     = (float*)alloc((size_t)NN * 4);
  float* pp      = (float*)alloc((size_t)NN * 4);
  float* qq      = (float*)alloc((size_t)NN * 4);
  float* uA1     = (float*)alloc((size_t)NN * 4);
  float* uA2     = (float*)alloc((size_t)NN * 4);
  float* uB1     = (float*)alloc((size_t)NN * 4);
  float* uB2     = (float*)alloc((size_t)NN * 4);
  float* x12     = (float*)alloc((size_t)NN * 12 * 4);
  float* mean12  = (float*)alloc((size_t)NN * 12 * 4);
  float* x1a     = (float*)alloc((size_t)NN * 128 * 4);
  float* mean128 = (float*)alloc((size_t)NN * 128 * 4);
  float* x1b     = (float*)alloc((size_t)NN * 128 * 4);

  // Region 1 (reuses x1a after k_mm2): Pa[32] zaA[8] zbA[8] x2a[8] P2[4]
  float* Pa  = x1a;
  float* zaA = x1a + (size_t)NN * 32;
  float* zbA = x1a + (size_t)NN * 40;
  float* x2a = x1a + (size_t)NN * 48;
  float* P2  = x1a + (size_t)NN * 56;
  // Region 2 (reuses mean128 after k_mm2): Pb[56] zaB[8] zbB[8] x3a[8] P2b[7]
  float* Pb  = mean128;
  float* zaB = mean128 + (size_t)NN * 56;
  float* zbB = mean128 + (size_t)NN * 64;
  float* x3a = mean128 + (size_t)NN * 72;
  float* P2b = mean128 + (size_t)NN * 80;

  // ---- CSR build ----
  hipMemsetAsync(cnt, 0, (size_t)NN * 4, stream);
  k_count<<<(EE + 255) / 256, 256, 0, stream>>>(ei, cnt);
  k_bsum<<<NB, 1024, 0, stream>>>(cnt, bsum);
  k_bscan<<<1, 128, 0, stream>>>(bsum, bexcl);
  k_bapply<<<NB, 1024, 0, stream>>>(cnt, bexcl, csr_off, cursor, dis);
  k_fill<<<(EE + 255) / 256, 256, 0, stream>>>(ei, cursor, csr_src);

  // ---- degree sort ----
  hipMemsetAsync(hist, 0, NBIN * 4, stream);
  k_hist<<<(NN + 255) / 256, 256, 0, stream>>>(cnt, hist);
  k_binscan<<<1, 64, 0, stream>>>(hist, bincur);
  k_scatter<<<(NN + 255) / 256, 256, 0, stream>>>(cnt, bincur, perm);

  // ---- SAGE chain ----
  k_pad12<<<(NN * 12 + 255) / 256, 256, 0, stream>>>(x, x12);
  k_gmean12<<<(NN + 63) / 64, 256, 0, stream>>>(x12, perm, csr_off, csr_src, mean12);
  k_sage_mm<11, 11><<<(NN + 63) / 64, 256, 0, stream>>>(mean12, 12, x, 11, s1wl, s1wr, s1b, x1a, 1);
  k_gather128<<<(NN + 7) / 8, 256, 0, stream>>>(x1a, perm, csr_off, csr_src, mean128);
  k_mm2<<<(NN + 127) / 128, 256, 0, stream>>>(mean128, x1a, s2wl, s2wr, s2b, x1b, 1);
  k_proj2<<<(NN + 255) / 256, 256, 0, stream>>>(x1b, s3wl, s3wr, pp, qq);
  k_g1_single<0><<<(NN + 63) / 64, 256, 0, stream>>>(
      pp, 1, qq, 1, s3b, 2, perm, csr_off, csr_src, dis, x1s);

  // ---- TAG P precompute (after k_mm2 frees x1a/mean128 regions) ----
  k_tagP<11, 4, 8><<<(NN + 255) / 256, 256, 0, stream>>>(x, 11, t1aw, Pa, 32);
  k_tagP<11, 7, 8><<<(NN + 255) / 256, 256, 0, stream>>>(x, 11, t1bw, Pb, 56);

  // ---- fused D=8 hops (chain a: 3 hops; chain b: 6 hops) ----
  k_g8_dual<<<(NN + 127) / 128, 256, 0, stream>>>(
      Pa + 24, 8, Pa + 16, 8, nullptr, 0,
      Pb + 48, 14, Pb + 40, 14, nullptr, 0,
      perm, csr_off, csr_src, dis, zaA, 2, zaB, 2);
  k_g8_dual<<<(NN + 127) / 128, 256, 0, stream>>>(
      zaA, 2, Pa + 8, 8, nullptr, 0,
      zaB, 2, Pb + 32, 14, nullptr, 0,
      perm, csr_off, csr_src, dis, zbA, 2, zbB, 2);
  k_g8_dual<<<(NN + 127) / 128, 256, 0, stream>>>(
      zbA, 2, Pa, 8, t1ab, 1,
      zbB, 2, Pb + 24, 14, nullptr, 0,
      perm, csr_off, csr_src, dis, x2a, 2, zaB, 2);
  k_g8_single<<<(NN + 127) / 128, 256, 0, stream>>>(
      zaB, 2, Pb + 16, 14, nullptr, 0, perm, csr_off, csr_src, dis, zbB, 2);
  k_g8_single<<<(NN + 127) / 128, 256, 0, stream>>>(
      zbB, 2, Pb + 8, 14, nullptr, 0, perm, csr_off, csr_src, dis, zaB, 2);
  k_g8_single<<<(NN + 127) / 128, 256, 0, stream>>>(
      zaB, 2, Pb, 14, t1bb, 1, perm, csr_off, csr_src, dis, x3a, 2);

  // ---- second TAG linears ----
  k_tagP<8, 4, 1><<<(NN + 255) / 256, 256, 0, stream>>>(x2a, 8, t2aw, P2, 4);
  k_tagP<8, 7, 1><<<(NN + 255) / 256, 256, 0, stream>>>(x3a, 8, t2bw, P2b, 7);

  // ---- fused 1-dim hops ----
  k_g1_dual<1><<<(NN + 63) / 64, 256, 0, stream>>>(
      P2 + 3, 4, P2 + 2, 4, nullptr, 0,
      P2b + 6, 7, P2b + 5, 7, nullptr, 0,
      perm, csr_off, csr_src, dis, uA1, uB1);
  k_g1_dual<1><<<(NN + 63) / 64, 256, 0, stream>>>(
      uA1, 1, P2 + 1, 4, nullptr, 0,
      uB1, 1, P2b + 4, 7, nullptr, 0,
      perm, csr_off, csr_src, dis, uA2, uB2);
  k_g1_dual<1><<<(NN + 63) / 64, 256, 0, stream>>>(
      uA2, 1, P2, 4, t2ab, 2,
      uB2, 1, P2b + 3, 7, nullptr, 0,
      perm, csr_off, csr_src, dis, x2s, uB1);
  k_g1_single<1><<<(NN + 63) / 64, 256, 0, stream>>>(
      uB1, 1, P2b + 2, 7, nullptr, 0, perm, csr_off, csr_src, dis, uB2);
  k_g1_single<1><<<(NN + 63) / 64, 256, 0, stream>>>(
      uB2, 1, P2b + 1, 7, nullptr, 0, perm, csr_off, csr_src, dis, uB1);
  k_g1_single<1><<<(NN + 63) / 64, 256, 0, stream>>>(
      uB1, 1, P2b, 7, t2bb, 2, perm, csr_off, csr_src, dis, x3s);

  // ---- final combine ----
  k_final<<<(NN + 255) / 256, 256, 0, stream>>>(x1s, x2s, x3s, lw, lb, out);
}

// Round 3
// 995.626 us; speedup vs baseline: 1.6193x; 1.6193x over previous
//
#include <hip/hip_runtime.h>
#include <hip/hip_bf16.h>
#include <hip/hip_fp16.h>

#define NN 100000
#define EE 1600000
#define NB 98      // ceil(NN/1024)
#define NBIN 64

__device__ __forceinline__ float act_apply(float v, int act) {
  if (act == 1) return 1.0f / (1.0f + expf(-v));
  if (act == 2) return fmaxf(v, 0.0f);
  return v;
}
__device__ __forceinline__ float4 act4(float4 v, int act) {
  v.x = act_apply(v.x, act); v.y = act_apply(v.y, act);
  v.z = act_apply(v.z, act); v.w = act_apply(v.w, act);
  return v;
}
__device__ __forceinline__ float4 f4fma(float s, float4 v, float4 a) {
  a.x += s * v.x; a.y += s * v.y; a.z += s * v.z; a.w += s * v.w; return a;
}
__device__ __forceinline__ float4 f4add(float4 a, float4 b) {
  a.x += b.x; a.y += b.y; a.z += b.z; a.w += b.w; return a;
}
__device__ __forceinline__ float4 f4scale(float4 a, float s) {
  a.x *= s; a.y *= s; a.z *= s; a.w *= s; return a;
}
__device__ __forceinline__ float4 h4f(uint2 v) {
  __half2 a = *reinterpret_cast<__half2*>(&v.x);
  __half2 b = *reinterpret_cast<__half2*>(&v.y);
  float2 fa = __half22float2(a), fb = __half22float2(b);
  return make_float4(fa.x, fa.y, fb.x, fb.y);
}

// ---------------- CSR build ----------------
__global__ void k_count(const int* __restrict__ ei, int* __restrict__ cnt) {
  int e = blockIdx.x * blockDim.x + threadIdx.x;
  if (e < EE) atomicAdd(&cnt[ei[EE + e]], 1);
}

__global__ __launch_bounds__(1024) void k_bsum(const int* __restrict__ cnt, int* __restrict__ bsum) {
  int i = blockIdx.x * 1024 + threadIdx.x;
  int v = (i < NN) ? cnt[i] : 0;
  for (int d = 1; d < 64; d <<= 1) v += __shfl_xor(v, d, 64);
  __shared__ int ws[16];
  int lane = threadIdx.x & 63, wid = threadIdx.x >> 6;
  if (lane == 0) ws[wid] = v;
  __syncthreads();
  if (threadIdx.x == 0) {
    int s = 0;
    for (int j = 0; j < 16; ++j) s += ws[j];
    bsum[blockIdx.x] = s;
  }
}

__global__ void k_bscan(const int* __restrict__ bsum, int* __restrict__ bexcl) {
  __shared__ int sh[128];
  int tid = threadIdx.x;
  int v = (tid < NB) ? bsum[tid] : 0;
  sh[tid] = v;
  __syncthreads();
  for (int d = 1; d < 128; d <<= 1) {
    int t = (tid >= d) ? sh[tid - d] : 0;
    __syncthreads();
    sh[tid] += t;
    __syncthreads();
  }
  if (tid < NB) bexcl[tid] = sh[tid] - v;
}

__global__ __launch_bounds__(1024) void k_bapply(const int* __restrict__ cnt,
                                                 const int* __restrict__ bexcl,
                                                 int* __restrict__ off, int* __restrict__ cursor,
                                                 float* __restrict__ dis) {
  int i = blockIdx.x * 1024 + threadIdx.x;
  int v = (i < NN) ? cnt[i] : 0;
  int lane = threadIdx.x & 63, wid = threadIdx.x >> 6;
  int incl = v;
  for (int d = 1; d < 64; d <<= 1) {
    int t = __shfl_up(incl, d, 64);
    if (lane >= d) incl += t;
  }
  __shared__ int ws[16];
  if (lane == 63) ws[wid] = incl;
  __syncthreads();
  if (threadIdx.x == 0) {
    int run = 0;
    for (int j = 0; j < 16; ++j) { int t = ws[j]; ws[j] = run; run += t; }
  }
  __syncthreads();
  int ex = incl - v + ws[wid] + bexcl[blockIdx.x];
  if (i < NN) {
    off[i] = ex;
    cursor[i] = ex;
    dis[i] = (v > 0) ? rsqrtf((float)v) : 0.0f;
  }
  if (blockIdx.x == 0 && threadIdx.x == 0) off[NN] = EE;
}

__global__ void k_fill(const int* __restrict__ ei, int* __restrict__ cursor,
                       int* __restrict__ csr_src) {
  int e = blockIdx.x * blockDim.x + threadIdx.x;
  if (e < EE) {
    int d = ei[EE + e];
    int pos = atomicAdd(&cursor[d], 1);
    csr_src[pos] = ei[e];
  }
}

// ---------------- degree sort (perm), LDS-aggregated atomics ----------------
__global__ __launch_bounds__(256) void k_hist(const int* __restrict__ cnt, int* __restrict__ hist) {
  __shared__ int lh[NBIN];
  if (threadIdx.x < NBIN) lh[threadIdx.x] = 0;
  __syncthreads();
  int i = blockIdx.x * 256 + threadIdx.x;
  if (i < NN) atomicAdd(&lh[min(cnt[i], NBIN - 1)], 1);
  __syncthreads();
  if (threadIdx.x < NBIN) {
    int v = lh[threadIdx.x];
    if (v) atomicAdd(&hist[threadIdx.x], v);
  }
}
__global__ void k_binscan(const int* __restrict__ hist, int* __restrict__ bincur) {
  int tid = threadIdx.x;
  int v = hist[tid];
  int incl = v;
  for (int d = 1; d < 64; d <<= 1) {
    int t = __shfl_up(incl, d, 64);
    if (tid >= d) incl += t;
  }
  bincur[tid] = incl - v;
}
__global__ __launch_bounds__(256) void k_scatter(const int* __restrict__ cnt,
                                                 int* __restrict__ bincur,
                                                 int* __restrict__ perm) {
  __shared__ int lh[NBIN];
  __shared__ int lbase[NBIN];
  if (threadIdx.x < NBIN) lh[threadIdx.x] = 0;
  __syncthreads();
  int i = blockIdx.x * 256 + threadIdx.x;
  int b = 0, r = 0;
  bool valid = i < NN;
  if (valid) {
    b = min(cnt[i], NBIN - 1);
    r = atomicAdd(&lh[b], 1);
  }
  __syncthreads();
  if (threadIdx.x < NBIN) {
    int v = lh[threadIdx.x];
    lbase[threadIdx.x] = v ? atomicAdd(&bincur[threadIdx.x], v) : 0;
  }
  __syncthreads();
  if (valid) perm[lbase[b] + r] = i;
}

// ---------------- pad x [N,11] -> [N,12] ----------------
__global__ void k_pad12(const float* __restrict__ x, float* __restrict__ x12) {
  int i = blockIdx.x * blockDim.x + threadIdx.x;
  if (i >= NN * 12) return;
  int n = i / 12, j = i - n * 12;
  x12[i] = (j < 11) ? x[n * 11 + j] : 0.0f;
}

// ---------------- gathers ----------------
// mean over neighbors, D=12 (padded), G=4 (t<3 active), float4
__global__ void k_gmean12(const float* __restrict__ x12, const int* __restrict__ perm,
                          const int* __restrict__ off, const int* __restrict__ srcarr,
                          float* __restrict__ out) {
  int g = blockIdx.x * 64 + (threadIdx.x >> 2);
  int t = threadIdx.x & 3;
  if (g >= NN || t >= 3) return;
  int node = perm[g];
  int s = off[node], e = off[node + 1];
  const float4* h4 = (const float4*)x12;
  float4 acc = {0, 0, 0, 0};
  int p = s;
  for (; p + 4 <= e; p += 4) {
    int s0 = srcarr[p], s1 = srcarr[p + 1], s2 = srcarr[p + 2], s3 = srcarr[p + 3];
    float4 v0 = h4[(long)s0 * 3 + t], v1 = h4[(long)s1 * 3 + t];
    float4 v2 = h4[(long)s2 * 3 + t], v3 = h4[(long)s3 * 3 + t];
    acc = f4add(acc, f4add(f4add(v0, v1), f4add(v2, v3)));
  }
  for (; p < e; ++p) {
    int s0 = srcarr[p];
    acc = f4add(acc, h4[(long)s0 * 3 + t]);
  }
  int c = e - s;
  float inv = 1.0f / (float)(c > 0 ? c : 1);
  ((float4*)out)[(long)node * 3 + t] = f4scale(acc, inv);
}

// mean over neighbors, D=128 fp16 input, G=32 (4 halves = 8B per lane), f32 accum
__global__ void k_gather128(const __half* __restrict__ h, const int* __restrict__ perm,
                            const int* __restrict__ off, const int* __restrict__ srcarr,
                            float* __restrict__ out) {
  int g = blockIdx.x * 8 + (threadIdx.x >> 5);
  int t = threadIdx.x & 31;
  if (g >= NN) return;
  int node = perm[g];
  int s = off[node], e = off[node + 1];
  const uint2* h4 = (const uint2*)h;   // 4 halves per uint2; row stride 32
  float4 acc = {0, 0, 0, 0};
  int p = s;
  for (; p + 4 <= e; p += 4) {
    int s0 = srcarr[p], s1 = srcarr[p + 1], s2 = srcarr[p + 2], s3 = srcarr[p + 3];
    uint2 r0 = h4[(long)s0 * 32 + t], r1 = h4[(long)s1 * 32 + t];
    uint2 r2 = h4[(long)s2 * 32 + t], r3 = h4[(long)s3 * 32 + t];
    acc = f4add(acc, f4add(f4add(h4f(r0), h4f(r1)), f4add(h4f(r2), h4f(r3))));
  }
  for (; p < e; ++p) {
    int s0 = srcarr[p];
    acc = f4add(acc, h4f(h4[(long)s0 * 32 + t]));
  }
  int c = e - s;
  float inv = 1.0f / (float)(c > 0 ? c : 1);
  ((float4*)out)[(long)node * 32 + t] = f4scale(acc, inv);
}

// TAG-norm D=8 gather, dual streams; all operands contiguous [N][8] (stride 2 float4)
__global__ void k_g8_dual(
    const float* __restrict__ ha, const float* __restrict__ adda,
    const float* __restrict__ biasa, int acta,
    const float* __restrict__ hb, const float* __restrict__ addb,
    const float* __restrict__ biasb, int actb,
    const int* __restrict__ perm, const int* __restrict__ off,
    const int* __restrict__ srcarr, const float* __restrict__ dis,
    float* __restrict__ outa, float* __restrict__ outb) {
  int g = blockIdx.x * 128 + (threadIdx.x >> 1);
  int t = threadIdx.x & 1;
  if (g >= NN) return;
  int node = perm[g];
  int s = off[node], e = off[node + 1];
  const float4* ha4 = (const float4*)ha;
  const float4* hb4 = (const float4*)hb;
  float4 accA = {0, 0, 0, 0}, accB = {0, 0, 0, 0};
  int p = s;
  for (; p + 2 <= e; p += 2) {
    int s0 = srcarr[p], s1 = srcarr[p + 1];
    float d0 = dis[s0], d1 = dis[s1];
    float4 a0 = ha4[(long)s0 * 2 + t], a1 = ha4[(long)s1 * 2 + t];
    float4 b0 = hb4[(long)s0 * 2 + t], b1 = hb4[(long)s1 * 2 + t];
    accA = f4fma(d0, a0, accA); accA = f4fma(d1, a1, accA);
    accB = f4fma(d0, b0, accB); accB = f4fma(d1, b1, accB);
  }
  if (p < e) {
    int s0 = srcarr[p];
    float d0 = dis[s0];
    accA = f4fma(d0, ha4[(long)s0 * 2 + t], accA);
    accB = f4fma(d0, hb4[(long)s0 * 2 + t], accB);
  }
  float dn = dis[node];
  float4 rA = f4scale(accA, dn);
  rA = f4add(rA, ((const float4*)adda)[(long)node * 2 + t]);
  if (biasa) rA = f4add(rA, ((const float4*)biasa)[t]);
  ((float4*)outa)[(long)node * 2 + t] = act4(rA, acta);
  float4 rB = f4scale(accB, dn);
  rB = f4add(rB, ((const float4*)addb)[(long)node * 2 + t]);
  if (biasb) rB = f4add(rB, ((const float4*)biasb)[t]);
  ((float4*)outb)[(long)node * 2 + t] = act4(rB, actb);
}

__global__ void k_g8_single(
    const float* __restrict__ ha, const float* __restrict__ adda,
    const float* __restrict__ biasa, int acta,
    const int* __restrict__ perm, const int* __restrict__ off,
    const int* __restrict__ srcarr, const float* __restrict__ dis,
    float* __restrict__ outa) {
  int g = blockIdx.x * 128 + (threadIdx.x >> 1);
  int t = threadIdx.x & 1;
  if (g >= NN) return;
  int node = perm[g];
  int s = off[node], e = off[node + 1];
  const float4* ha4 = (const float4*)ha;
  float4 accA = {0, 0, 0, 0};
  int p = s;
  for (; p + 4 <= e; p += 4) {
    int s0 = srcarr[p], s1 = srcarr[p + 1], s2 = srcarr[p + 2], s3 = srcarr[p + 3];
    float d0 = dis[s0], d1 = dis[s1], d2 = dis[s2], d3 = dis[s3];
    accA = f4fma(d0, ha4[(long)s0 * 2 + t], accA);
    accA = f4fma(d1, ha4[(long)s1 * 2 + t], accA);
    accA = f4fma(d2, ha4[(long)s2 * 2 + t], accA);
    accA = f4fma(d3, ha4[(long)s3 * 2 + t], accA);
  }
  for (; p < e; ++p) {
    int s0 = srcarr[p];
    accA = f4fma(dis[s0], ha4[(long)s0 * 2 + t], accA);
  }
  float4 rA = f4scale(accA, dis[node]);
  rA = f4add(rA, ((const float4*)adda)[(long)node * 2 + t]);
  if (biasa) rA = f4add(rA, ((const float4*)biasa)[t]);
  ((float4*)outa)[(long)node * 2 + t] = act4(rA, acta);
}

// 1-dim gathers: G=4 lanes per node, shuffle reduce. MODE 0 = SAGE mean, 1 = TAG norm.
// All operands contiguous [N].
template<int MODE>
__global__ void k_g1_dual(
    const float* __restrict__ ua, const float* __restrict__ adda,
    const float* __restrict__ biasa, int acta,
    const float* __restrict__ ub, const float* __restrict__ addb,
    const float* __restrict__ biasb, int actb,
    const int* __restrict__ perm, const int* __restrict__ off,
    const int* __restrict__ srcarr, const float* __restrict__ dis,
    float* __restrict__ outa, float* __restrict__ outb) {
  int g = blockIdx.x * 64 + (threadIdx.x >> 2);
  int t = threadIdx.x & 3;
  if (g >= NN) return;
  int node = perm[g];
  int s = off[node], e = off[node + 1];
  float accA = 0.0f, accB = 0.0f;
  for (int p = s + t; p < e; p += 4) {
    int s0 = srcarr[p];
    float d = (MODE == 1) ? dis[s0] : 1.0f;
    accA += d * ua[s0];
    accB += d * ub[s0];
  }
  accA += __shfl_xor(accA, 1, 64); accA += __shfl_xor(accA, 2, 64);
  accB += __shfl_xor(accB, 1, 64); accB += __shfl_xor(accB, 2, 64);
  if (t == 0) {
    float sc;
    if (MODE == 0) { int c = e - s; sc = 1.0f / (float)(c > 0 ? c : 1); }
    else sc = dis[node];
    float rA = accA * sc + adda[node];
    if (biasa) rA += biasa[0];
    outa[node] = act_apply(rA, acta);
    float rB = accB * sc + addb[node];
    if (biasb) rB += biasb[0];
    outb[node] = act_apply(rB, actb);
  }
}

template<int MODE>
__global__ void k_g1_single(
    const float* __restrict__ ua, const float* __restrict__ adda,
    const float* __restrict__ biasa, int acta,
    const int* __restrict__ perm, const int* __restrict__ off,
    const int* __restrict__ srcarr, const float* __restrict__ dis,
    float* __restrict__ outa) {
  int g = blockIdx.x * 64 + (threadIdx.x >> 2);
  int t = threadIdx.x & 3;
  if (g >= NN) return;
  int node = perm[g];
  int s = off[node], e = off[node + 1];
  float accA = 0.0f;
  for (int p = s + t; p < e; p += 4) {
    int s0 = srcarr[p];
    float d = (MODE == 1) ? dis[s0] : 1.0f;
    accA += d * ua[s0];
  }
  accA += __shfl_xor(accA, 1, 64); accA += __shfl_xor(accA, 2, 64);
  if (t == 0) {
    float sc;
    if (MODE == 0) { int c = e - s; sc = 1.0f / (float)(c > 0 ? c : 1); }
    else sc = dis[node];
    float rA = accA * sc + adda[node];
    if (biasa) rA += biasa[0];
    outa[node] = act_apply(rA, acta);
  }
}

// ---------------- SAGE layer-1 fused GEMM (small K), fp16 output ----------------
template<int K1, int K2>
__global__ __launch_bounds__(256) void k_sage_mm(
    const float* __restrict__ A1, int as1, const float* __restrict__ A2, int as2,
    const float* __restrict__ W1, const float* __restrict__ W2,
    const float* __restrict__ bias, __half* __restrict__ out, int act) {
  constexpr int K = K1 + K2;
  constexpr int BM = 64;
  constexpr int BK = 32;
  __shared__ float Ash[BK][BM];
  __shared__ float Wsh[BK][128];
  int m0 = blockIdx.x * BM;
  int tid = threadIdx.x;
  int tx = tid & 15, ty = tid >> 4;
  int tm = ty * 4;
  int to = tx * 8;
  float acc[4][8] = {};
  for (int k0 = 0; k0 < K; k0 += BK) {
    {
      int mm = tid % BM, kb = tid / BM;
      #pragma unroll
      for (int it = 0; it < BK / 4; ++it) {
        int kk = kb + 4 * it;
        int gk = k0 + kk, gm = m0 + mm;
        float v = 0.0f;
        if (gm < NN && gk < K)
          v = (gk < K1) ? A1[(long)gm * as1 + gk] : A2[(long)gm * as2 + (gk - K1)];
        Ash[kk][mm] = v;
      }
    }
    {
      int oo = tid % 128, kb = tid / 128;
      #pragma unroll
      for (int it = 0; it < BK / 2; ++it) {
        int kk = kb + 2 * it;
        int gk = k0 + kk;
        float v = 0.0f;
        if (gk < K)
          v = (gk < K1) ? W1[oo * K1 + gk] : W2[oo * K2 + (gk - K1)];
        Wsh[kk][oo] = v;
      }
    }
    __syncthreads();
    #pragma unroll
    for (int kk = 0; kk < BK; ++kk) {
      float4 av = *reinterpret_cast<const float4*>(&Ash[kk][tm]);
      float4 wv0 = *reinterpret_cast<const float4*>(&Wsh[kk][to]);
      float4 wv1 = *reinterpret_cast<const float4*>(&Wsh[kk][to + 4]);
      float a[4] = {av.x, av.y, av.z, av.w};
      float w[8] = {wv0.x, wv0.y, wv0.z, wv0.w, wv1.x, wv1.y, wv1.z, wv1.w};
      #pragma unroll
      for (int i2 = 0; i2 < 4; ++i2)
        #pragma unroll
        for (int j = 0; j < 8; ++j)
          acc[i2][j] += a[i2] * w[j];
    }
    __syncthreads();
  }
  #pragma unroll
  for (int i2 = 0; i2 < 4; ++i2) {
    int gm = m0 + tm + i2;
    if (gm >= NN) continue;
    __half2* orow = (__half2*)(out + (long)gm * 128);
    #pragma unroll
    for (int j = 0; j < 4; ++j) {
      float lo = act_apply(acc[i2][2 * j] + bias[to + 2 * j], act);
      float hi = act_apply(acc[i2][2 * j + 1] + bias[to + 2 * j + 1], act);
      orow[to / 2 + j] = __floats2half2_rn(lo, hi);
    }
  }
}

// ---------------- SAGE layer-2 GEMM: A1 f32, A2 fp16; 128x128 tile ----------------
__global__ __launch_bounds__(256) void k_mm2(
    const float* __restrict__ A1, const __half* __restrict__ A2,
    const float* __restrict__ W1, const float* __restrict__ W2,
    const float* __restrict__ bias, float* __restrict__ out, int act) {
  __shared__ float Ash[16][132];
  __shared__ float Wsh[16][132];
  int tid = threadIdx.x;
  int m0 = blockIdx.x * 128;
  int r = tid >> 2;
  int c = tid & 3;
  int tx = tid & 15, ty = tid >> 4;
  int tm = ty * 8;
  int to = tx * 4;
  float acc[8][8] = {};
  for (int k0 = 0; k0 < 256; k0 += 16) {
    const float* Wsrc;
    int kk0;
    bool first = (k0 < 128);
    if (first) { Wsrc = W1; kk0 = k0; }
    else { Wsrc = W2; kk0 = k0 - 128; }
    #pragma unroll
    for (int h = 0; h < 2; ++h) {
      int row = r + h * 64;
      int gm = m0 + row;
      float4 v = {0, 0, 0, 0};
      if (gm < NN) {
        if (first) v = *(const float4*)&A1[(long)gm * 128 + kk0 + c * 4];
        else       v = h4f(*(const uint2*)&A2[(long)gm * 128 + kk0 + c * 4]);
      }
      Ash[c * 4 + 0][row] = v.x; Ash[c * 4 + 1][row] = v.y;
      Ash[c * 4 + 2][row] = v.z; Ash[c * 4 + 3][row] = v.w;
    }
    #pragma unroll
    for (int h = 0; h < 2; ++h) {
      int oo = r + h * 64;
      float4 v = *(const float4*)&Wsrc[oo * 128 + kk0 + c * 4];
      Wsh[c * 4 + 0][oo] = v.x; Wsh[c * 4 + 1][oo] = v.y;
      Wsh[c * 4 + 2][oo] = v.z; Wsh[c * 4 + 3][oo] = v.w;
    }
    __syncthreads();
    #pragma unroll
    for (int kk = 0; kk < 16; ++kk) {
      float a[8], w[8];
      *(float4*)&a[0] = *(const float4*)&Ash[kk][tm];
      *(float4*)&a[4] = *(const float4*)&Ash[kk][tm + 4];
      *(float4*)&w[0] = *(const float4*)&Wsh[kk][to];
      *(float4*)&w[4] = *(const float4*)&Wsh[kk][to + 64];
      #pragma unroll
      for (int i = 0; i < 8; ++i)
        #pragma unroll
        for (int j = 0; j < 8; ++j)
          acc[i][j] += a[i] * w[j];
    }
    __syncthreads();
  }
  #pragma unroll
  for (int i = 0; i < 8; ++i) {
    int gm = m0 + tm + i;
    if (gm >= NN) continue;
    float4 o0, o1;
    o0.x = act_apply(acc[i][0] + bias[to + 0], act);
    o0.y = act_apply(acc[i][1] + bias[to + 1], act);
    o0.z = act_apply(acc[i][2] + bias[to + 2], act);
    o0.w = act_apply(acc[i][3] + bias[to + 3], act);
    o1.x = act_apply(acc[i][4] + bias[to + 64], act);
    o1.y = act_apply(acc[i][5] + bias[to + 65], act);
    o1.z = act_apply(acc[i][6] + bias[to + 66], act);
    o1.w = act_apply(acc[i][7] + bias[to + 67], act);
    *(float4*)&out[(long)gm * 128 + to] = o0;
    *(float4*)&out[(long)gm * 128 + to + 64] = o1;
  }
}

// ---------------- TAG P-precompute, hop-major output [NH][N][NO] ----------------
template<int KIN, int NH, int NO>
__global__ void k_tagP(const float* __restrict__ A, int as,
                       const float* __restrict__ w, float* __restrict__ out) {
  int i = blockIdx.x * blockDim.x + threadIdx.x;
  if (i >= NN) return;
  float a[KIN];
  #pragma unroll
  for (int j = 0; j < KIN; ++j) a[j] = A[(long)i * as + j];
  #pragma unroll
  for (int k = 0; k < NH; ++k) {
    #pragma unroll
    for (int o = 0; o < NO; ++o) {
      float s = 0.0f;
      #pragma unroll
      for (int j = 0; j < KIN; ++j) s += a[j] * w[o * (KIN * NH) + k * KIN + j];
      out[((long)k * NN + i) * NO + o] = s;
    }
  }
}

__global__ void k_proj2(const float* __restrict__ A, const float* __restrict__ w1,
                        const float* __restrict__ w2, float* __restrict__ P,
                        float* __restrict__ Q) {
  int i = blockIdx.x * blockDim.x + threadIdx.x;
  if (i >= NN) return;
  const float4* a4 = reinterpret_cast<const float4*>(A + (long)i * 128);
  float s1 = 0.0f, s2 = 0.0f;
  #pragma unroll
  for (int k = 0; k < 32; ++k) {
    float4 v = a4[k];
    s1 += v.x * w1[4 * k] + v.y * w1[4 * k + 1] + v.z * w1[4 * k + 2] + v.w * w1[4 * k + 3];
    s2 += v.x * w2[4 * k] + v.y * w2[4 * k + 1] + v.z * w2[4 * k + 2] + v.w * w2[4 * k + 3];
  }
  P[i] = s1;
  Q[i] = s2;
}

__global__ void k_final(const float* __restrict__ x1, const float* __restrict__ x2,
                        const float* __restrict__ x3, const float* __restrict__ lw,
                        const float* __restrict__ lb, float* __restrict__ out) {
  int i = blockIdx.x * blockDim.x + threadIdx.x;
  if (i >= NN) return;
  float v = x1[i] * lw[0] + x2[i] * lw[1] + x3[i] * lw[2] + lb[0];
  out[i] = fmaxf(v, 0.0f);
}

extern "C" void kernel_launch(void* const* d_in, const int* in_sizes, int n_in,
                              void* d_out, int out_size, void* d_ws, size_t ws_size,
                              hipStream_t stream) {
  const float* x    = (const float*)d_in[0];
  const int*   ei   = (const int*)d_in[1];
  const float* s1wl = (const float*)d_in[2];
  const float* s1wr = (const float*)d_in[3];
  const float* s1b  = (const float*)d_in[4];
  const float* s2wl = (const float*)d_in[5];
  const float* s2wr = (const float*)d_in[6];
  const float* s2b  = (const float*)d_in[7];
  const float* s3wl = (const float*)d_in[8];
  const float* s3wr = (const float*)d_in[9];
  const float* s3b  = (const float*)d_in[10];
  const float* t1aw = (const float*)d_in[11];
  const float* t1ab = (const float*)d_in[12];
  const float* t2aw = (const float*)d_in[13];
  const float* t2ab = (const float*)d_in[14];
  const float* t1bw = (const float*)d_in[15];
  const float* t1bb = (const float*)d_in[16];
  const float* t2bw = (const float*)d_in[17];
  const float* t2bb = (const float*)d_in[18];
  const float* lw   = (const float*)d_in[19];
  const float* lb   = (const float*)d_in[20];
  float* out = (float*)d_out;

  char* basep = (char*)d_ws;
  size_t off = 0;
  auto alloc = [&](size_t bytes) -> void* {
    void* ptr = basep + off;
    off = (off + bytes + 255) & ~(size_t)255;
    return ptr;
  };
  int*   cnt     = (int*)alloc((size_t)NN * 4);
  int*   csr_off = (int*)alloc((size_t)(NN + 1) * 4);
  int*   cursor  = (int*)alloc((size_t)NN * 4);
  float* dis     = (float*)alloc((size_t)NN * 4);
  int*   csr_src = (int*)alloc((size_t)EE * 4);
  int*   perm    = (int*)alloc((size_t)NN * 4);
  int*   bsum    = (int*)alloc(128 * 4);
  int*   bexcl   = (int*)alloc(128 * 4);
  int*   hist    = (int*)alloc(NBIN * 4);
  int*   bincur  = (int*)alloc(NBIN * 4);
  float* x1s     = (float*)alloc((size_t)NN * 4);
  float* x2s     = (float*)alloc((size_t)NN * 4);
  float* x3s     = (float*)alloc((size_t)NN * 4);
  float* pp      = (float*)alloc((size_t)NN * 4);
  float* qq      = (float*)alloc((size_t)NN * 4);
  float* uA1     = (float*)alloc((size_t)NN * 4);
  float* uA2     = (float*)alloc((size_t)NN * 4);
  float* uB1     = (float*)alloc((size_t)NN * 4);
  float* uB2     = (float*)alloc((size_t)NN * 4);
  float* x12     = (float*)alloc((size_t)NN * 12 * 4);
  float* mean12  = (float*)alloc((size_t)NN * 12 * 4);
  __half* x1a_h  = (__half*)alloc((size_t)NN * 128 * 2);   // fp16 x1a, region1 overlay
  float* mean128 = (float*)alloc((size_t)NN * 128 * 4);    // region2 overlay
  float* x1b     = (float*)alloc((size_t)NN * 128 * 4);

  // Region 1 overlay (x1a_h spans N*64 float-equivalents; reused after k_mm2):
  float* r1 = (float*)x1a_h;
  float* Pa  = r1;                      // [4][N][8]  = 32N floats
  float* zaA = r1 + (size_t)NN * 32;    // [N][8]
  float* zbA = r1 + (size_t)NN * 40;    // [N][8]
  float* x2a = r1 + (size_t)NN * 48;    // [N][8]
  float* P2  = r1 + (size_t)NN * 56;    // [4][N] = 4N floats (<= 64N total ok)
  // Region 2 overlay (mean128 = 128N floats; reused after k_mm2):
  float* Pb  = mean128;                      // [7][N][8] = 56N
  float* zaB = mean128 + (size_t)NN * 56;    // [N][8]
  float* zbB = mean128 + (size_t)NN * 64;    // [N][8]
  float* x3a = mean128 + (size_t)NN * 72;    // [N][8]
  float* P2b = mean128 + (size_t)NN * 80;    // [7][N] = 7N

  // ---- CSR build ----
  hipMemsetAsync(cnt, 0, (size_t)NN * 4, stream);
  k_count<<<(EE + 255) / 256, 256, 0, stream>>>(ei, cnt);
  k_bsum<<<NB, 1024, 0, stream>>>(cnt, bsum);
  k_bscan<<<1, 128, 0, stream>>>(bsum, bexcl);
  k_bapply<<<NB, 1024, 0, stream>>>(cnt, bexcl, csr_off, cursor, dis);
  k_fill<<<(EE + 255) / 256, 256, 0, stream>>>(ei, cursor, csr_src);

  // ---- degree sort ----
  hipMemsetAsync(hist, 0, NBIN * 4, stream);
  k_hist<<<(NN + 255) / 256, 256, 0, stream>>>(cnt, hist);
  k_binscan<<<1, 64, 0, stream>>>(hist, bincur);
  k_scatter<<<(NN + 255) / 256, 256, 0, stream>>>(cnt, bincur, perm);

  // ---- SAGE chain ----
  k_pad12<<<(NN * 12 + 255) / 256, 256, 0, stream>>>(x, x12);
  k_gmean12<<<(NN + 63) / 64, 256, 0, stream>>>(x12, perm, csr_off, csr_src, mean12);
  k_sage_mm<11, 11><<<(NN + 63) / 64, 256, 0, stream>>>(mean12, 12, x, 11, s1wl, s1wr, s1b, x1a_h, 1);
  k_gather128<<<(NN + 7) / 8, 256, 0, stream>>>(x1a_h, perm, csr_off, csr_src, mean128);
  k_mm2<<<(NN + 127) / 128, 256, 0, stream>>>(mean128, x1a_h, s2wl, s2wr, s2b, x1b, 1);
  k_proj2<<<(NN + 255) / 256, 256, 0, stream>>>(x1b, s3wl, s3wr, pp, qq);
  k_g1_single<0><<<(NN + 63) / 64, 256, 0, stream>>>(
      pp, qq, s3b, 2, perm, csr_off, csr_src, dis, x1s);

  // ---- TAG P precompute (after k_mm2 frees region1/region2) ----
  k_tagP<11, 4, 8><<<(NN + 255) / 256, 256, 0, stream>>>(x, 11, t1aw, Pa);
  k_tagP<11, 7, 8><<<(NN + 255) / 256, 256, 0, stream>>>(x, 11, t1bw, Pb);

  const size_t S8 = (size_t)NN * 8;
  // ---- fused D=8 hops (chain a: 3 hops; chain b: 6 hops) ----
  k_g8_dual<<<(NN + 127) / 128, 256, 0, stream>>>(
      Pa + 3 * S8, Pa + 2 * S8, nullptr, 0,
      Pb + 6 * S8, Pb + 5 * S8, nullptr, 0,
      perm, csr_off, csr_src, dis, zaA, zaB);
  k_g8_dual<<<(NN + 127) / 128, 256, 0, stream>>>(
      zaA, Pa + 1 * S8, nullptr, 0,
      zaB, Pb + 4 * S8, nullptr, 0,
      perm, csr_off, csr_src, dis, zbA, zbB);
  k_g8_dual<<<(NN + 127) / 128, 256, 0, stream>>>(
      zbA, Pa, t1ab, 1,
      zbB, Pb + 3 * S8, nullptr, 0,
      perm, csr_off, csr_src, dis, x2a, zaB);
  k_g8_single<<<(NN + 127) / 128, 256, 0, stream>>>(
      zaB, Pb + 2 * S8, nullptr, 0, perm, csr_off, csr_src, dis, zbB);
  k_g8_single<<<(NN + 127) / 128, 256, 0, stream>>>(
      zbB, Pb + 1 * S8, nullptr, 0, perm, csr_off, csr_src, dis, zaB);
  k_g8_single<<<(NN + 127) / 128, 256, 0, stream>>>(
      zaB, Pb, t1bb, 1, perm, csr_off, csr_src, dis, x3a);

  // ---- second TAG linears (hop-major [NH][N]) ----
  k_tagP<8, 4, 1><<<(NN + 255) / 256, 256, 0, stream>>>(x2a, 8, t2aw, P2);
  k_tagP<8, 7, 1><<<(NN + 255) / 256, 256, 0, stream>>>(x3a, 8, t2bw, P2b);

  // ---- fused 1-dim hops ----
  k_g1_dual<1><<<(NN + 63) / 64, 256, 0, stream>>>(
      P2 + 3 * (size_t)NN, P2 + 2 * (size_t)NN, nullptr, 0,
      P2b + 6 * (size_t)NN, P2b + 5 * (size_t)NN, nullptr, 0,
      perm, csr_off, csr_src, dis, uA1, uB1);
  k_g1_dual<1><<<(NN + 63) / 64, 256, 0, stream>>>(
      uA1, P2 + 1 * (size_t)NN, nullptr, 0,
      uB1, P2b + 4 * (size_t)NN, nullptr, 0,
      perm, csr_off, csr_src, dis, uA2, uB2);
  k_g1_dual<1><<<(NN + 63) / 64, 256, 0, stream>>>(
      uA2, P2, t2ab, 2,
      uB2, P2b + 3 * (size_t)NN, nullptr, 0,
      perm, csr_off, csr_src, dis, x2s, uB1);
  k_g1_single<1><<<(NN + 63) / 64, 256, 0, stream>>>(
      uB1, P2b + 2 * (size_t)NN, nullptr, 0, perm, csr_off, csr_src, dis, uB2);
  k_g1_single<1><<<(NN + 63) / 64, 256, 0, stream>>>(
      uB2, P2b + 1 * (size_t)NN, nullptr, 0, perm, csr_off, csr_src, dis, uB1);
  k_g1_single<1><<<(NN + 63) / 64, 256, 0, stream>>>(
      uB1, P2b, t2bb, 2, perm, csr_off, csr_src, dis, x3s);

  // ---- final combine ----
  k_final<<<(NN + 255) / 256, 256, 0, stream>>>(x1s, x2s, x3s, lw, lb, out);
}

// Round 4
// 900.174 us; speedup vs baseline: 1.7910x; 1.1060x over previous
//
#include <hip/hip_runtime.h>
#include <hip/hip_bf16.h>
#include <hip/hip_fp16.h>

#define NN 100000
#define EE 1600000
#define NB 98      // ceil(NN/1024)
#define NBIN 64

typedef _Float16 h8v __attribute__((ext_vector_type(8)));
typedef float f4v __attribute__((ext_vector_type(4)));

__device__ __forceinline__ float act_apply(float v, int act) {
  if (act == 1) return 1.0f / (1.0f + expf(-v));
  if (act == 2) return fmaxf(v, 0.0f);
  return v;
}
__device__ __forceinline__ float4 act4(float4 v, int act) {
  v.x = act_apply(v.x, act); v.y = act_apply(v.y, act);
  v.z = act_apply(v.z, act); v.w = act_apply(v.w, act);
  return v;
}
__device__ __forceinline__ float4 f4fma(float s, float4 v, float4 a) {
  a.x += s * v.x; a.y += s * v.y; a.z += s * v.z; a.w += s * v.w; return a;
}
__device__ __forceinline__ float4 f4add(float4 a, float4 b) {
  a.x += b.x; a.y += b.y; a.z += b.z; a.w += b.w; return a;
}
__device__ __forceinline__ float4 f4scale(float4 a, float s) {
  a.x *= s; a.y *= s; a.z *= s; a.w *= s; return a;
}
__device__ __forceinline__ float4 h4f(uint2 v) {
  __half2 a = *reinterpret_cast<__half2*>(&v.x);
  __half2 b = *reinterpret_cast<__half2*>(&v.y);
  float2 fa = __half22float2(a), fb = __half22float2(b);
  return make_float4(fa.x, fa.y, fb.x, fb.y);
}
__device__ __forceinline__ void h8acc(uint4 v, float* a) {
  float4 lo = h4f(make_uint2(v.x, v.y));
  float4 hi = h4f(make_uint2(v.z, v.w));
  a[0] += lo.x; a[1] += lo.y; a[2] += lo.z; a[3] += lo.w;
  a[4] += hi.x; a[5] += hi.y; a[6] += hi.z; a[7] += hi.w;
}

// ---------------- CSR build ----------------
__global__ void k_count(const int* __restrict__ ei, int* __restrict__ cnt) {
  int e = blockIdx.x * blockDim.x + threadIdx.x;
  if (e < EE) atomicAdd(&cnt[ei[EE + e]], 1);
}

__global__ __launch_bounds__(1024) void k_bsum(const int* __restrict__ cnt, int* __restrict__ bsum) {
  int i = blockIdx.x * 1024 + threadIdx.x;
  int v = (i < NN) ? cnt[i] : 0;
  for (int d = 1; d < 64; d <<= 1) v += __shfl_xor(v, d, 64);
  __shared__ int ws[16];
  int lane = threadIdx.x & 63, wid = threadIdx.x >> 6;
  if (lane == 0) ws[wid] = v;
  __syncthreads();
  if (threadIdx.x == 0) {
    int s = 0;
    for (int j = 0; j < 16; ++j) s += ws[j];
    bsum[blockIdx.x] = s;
  }
}

__global__ void k_bscan(const int* __restrict__ bsum, int* __restrict__ bexcl) {
  __shared__ int sh[128];
  int tid = threadIdx.x;
  int v = (tid < NB) ? bsum[tid] : 0;
  sh[tid] = v;
  __syncthreads();
  for (int d = 1; d < 128; d <<= 1) {
    int t = (tid >= d) ? sh[tid - d] : 0;
    __syncthreads();
    sh[tid] += t;
    __syncthreads();
  }
  if (tid < NB) bexcl[tid] = sh[tid] - v;
}

__global__ __launch_bounds__(1024) void k_bapply(const int* __restrict__ cnt,
                                                 const int* __restrict__ bexcl,
                                                 int* __restrict__ off, int* __restrict__ cursor,
                                                 float* __restrict__ dis) {
  int i = blockIdx.x * 1024 + threadIdx.x;
  int v = (i < NN) ? cnt[i] : 0;
  int lane = threadIdx.x & 63, wid = threadIdx.x >> 6;
  int incl = v;
  for (int d = 1; d < 64; d <<= 1) {
    int t = __shfl_up(incl, d, 64);
    if (lane >= d) incl += t;
  }
  __shared__ int ws[16];
  if (lane == 63) ws[wid] = incl;
  __syncthreads();
  if (threadIdx.x == 0) {
    int run = 0;
    for (int j = 0; j < 16; ++j) { int t = ws[j]; ws[j] = run; run += t; }
  }
  __syncthreads();
  int ex = incl - v + ws[wid] + bexcl[blockIdx.x];
  if (i < NN) {
    off[i] = ex;
    cursor[i] = ex;
    dis[i] = (v > 0) ? rsqrtf((float)v) : 0.0f;
  }
  if (blockIdx.x == 0 && threadIdx.x == 0) off[NN] = EE;
}

__global__ void k_fill(const int* __restrict__ ei, int* __restrict__ cursor,
                       int* __restrict__ csr_src) {
  int e = blockIdx.x * blockDim.x + threadIdx.x;
  if (e < EE) {
    int d = ei[EE + e];
    int pos = atomicAdd(&cursor[d], 1);
    csr_src[pos] = ei[e];
  }
}

// ---------------- degree sort (perm), LDS-aggregated atomics ----------------
__global__ __launch_bounds__(256) void k_hist(const int* __restrict__ cnt, int* __restrict__ hist) {
  __shared__ int lh[NBIN];
  if (threadIdx.x < NBIN) lh[threadIdx.x] = 0;
  __syncthreads();
  int i = blockIdx.x * 256 + threadIdx.x;
  if (i < NN) atomicAdd(&lh[min(cnt[i], NBIN - 1)], 1);
  __syncthreads();
  if (threadIdx.x < NBIN) {
    int v = lh[threadIdx.x];
    if (v) atomicAdd(&hist[threadIdx.x], v);
  }
}
__global__ void k_binscan(const int* __restrict__ hist, int* __restrict__ bincur) {
  int tid = threadIdx.x;
  int v = hist[tid];
  int incl = v;
  for (int d = 1; d < 64; d <<= 1) {
    int t = __shfl_up(incl, d, 64);
    if (tid >= d) incl += t;
  }
  bincur[tid] = incl - v;
}
__global__ __launch_bounds__(256) void k_scatter(const int* __restrict__ cnt,
                                                 int* __restrict__ bincur,
                                                 int* __restrict__ perm) {
  __shared__ int lh[NBIN];
  __shared__ int lbase[NBIN];
  if (threadIdx.x < NBIN) lh[threadIdx.x] = 0;
  __syncthreads();
  int i = blockIdx.x * 256 + threadIdx.x;
  int b = 0, r = 0;
  bool valid = i < NN;
  if (valid) {
    b = min(cnt[i], NBIN - 1);
    r = atomicAdd(&lh[b], 1);
  }
  __syncthreads();
  if (threadIdx.x < NBIN) {
    int v = lh[threadIdx.x];
    lbase[threadIdx.x] = v ? atomicAdd(&bincur[threadIdx.x], v) : 0;
  }
  __syncthreads();
  if (valid) perm[lbase[b] + r] = i;
}

// ---------------- pad x [N,11] -> [N,12] ----------------
__global__ void k_pad12(const float* __restrict__ x, float* __restrict__ x12) {
  int i = blockIdx.x * blockDim.x + threadIdx.x;
  if (i >= NN * 12) return;
  int n = i / 12, j = i - n * 12;
  x12[i] = (j < 11) ? x[n * 11 + j] : 0.0f;
}

// ---------------- weight cast for MFMA: w2h[o][0:256] = [s2wl || s2wr] fp16 ----------------
__global__ void k_wcast(const float* __restrict__ wl, const float* __restrict__ wr,
                        __half* __restrict__ w2h) {
  int i = blockIdx.x * 256 + threadIdx.x;
  if (i >= 128 * 256) return;
  int o = i >> 8, k = i & 255;
  float v = (k < 128) ? wl[o * 128 + k] : wr[o * 128 + (k - 128)];
  w2h[i] = __float2half(v);
}

// ---------------- gathers ----------------
__global__ void k_gmean12(const float* __restrict__ x12, const int* __restrict__ perm,
                          const int* __restrict__ off, const int* __restrict__ srcarr,
                          float* __restrict__ out) {
  int g = blockIdx.x * 64 + (threadIdx.x >> 2);
  int t = threadIdx.x & 3;
  if (g >= NN || t >= 3) return;
  int node = perm[g];
  int s = off[node], e = off[node + 1];
  const float4* h4 = (const float4*)x12;
  float4 acc = {0, 0, 0, 0};
  int p = s;
  for (; p + 4 <= e; p += 4) {
    int s0 = srcarr[p], s1 = srcarr[p + 1], s2 = srcarr[p + 2], s3 = srcarr[p + 3];
    float4 v0 = h4[(long)s0 * 3 + t], v1 = h4[(long)s1 * 3 + t];
    float4 v2 = h4[(long)s2 * 3 + t], v3 = h4[(long)s3 * 3 + t];
    acc = f4add(acc, f4add(f4add(v0, v1), f4add(v2, v3)));
  }
  for (; p < e; ++p) {
    int s0 = srcarr[p];
    acc = f4add(acc, h4[(long)s0 * 3 + t]);
  }
  int c = e - s;
  float inv = 1.0f / (float)(c > 0 ? c : 1);
  ((float4*)out)[(long)node * 3 + t] = f4scale(acc, inv);
}

// mean over neighbors, D=128 fp16 in / fp16 out, G=16 lanes (uint4 = 8 halves each)
__global__ void k_gather128(const __half* __restrict__ h, const int* __restrict__ perm,
                            const int* __restrict__ off, const int* __restrict__ srcarr,
                            __half* __restrict__ outh) {
  int g = blockIdx.x * 16 + (threadIdx.x >> 4);
  int t = threadIdx.x & 15;
  if (g >= NN) return;
  int node = perm[g];
  int s = off[node], e = off[node + 1];
  const uint4* h4 = (const uint4*)h;   // 8 halves per uint4; row stride 16
  float acc[8] = {};
  int p = s;
  for (; p + 4 <= e; p += 4) {
    int s0 = srcarr[p], s1 = srcarr[p + 1], s2 = srcarr[p + 2], s3 = srcarr[p + 3];
    uint4 r0 = h4[(long)s0 * 16 + t], r1 = h4[(long)s1 * 16 + t];
    uint4 r2 = h4[(long)s2 * 16 + t], r3 = h4[(long)s3 * 16 + t];
    h8acc(r0, acc); h8acc(r1, acc); h8acc(r2, acc); h8acc(r3, acc);
  }
  for (; p < e; ++p) {
    int s0 = srcarr[p];
    h8acc(h4[(long)s0 * 16 + t], acc);
  }
  int c = e - s;
  float inv = 1.0f / (float)(c > 0 ? c : 1);
  uint4 o;
  __half2 p0 = __floats2half2_rn(acc[0] * inv, acc[1] * inv);
  __half2 p1 = __floats2half2_rn(acc[2] * inv, acc[3] * inv);
  __half2 p2 = __floats2half2_rn(acc[4] * inv, acc[5] * inv);
  __half2 p3 = __floats2half2_rn(acc[6] * inv, acc[7] * inv);
  o.x = *(unsigned*)&p0; o.y = *(unsigned*)&p1; o.z = *(unsigned*)&p2; o.w = *(unsigned*)&p3;
  ((uint4*)outh)[(long)node * 16 + t] = o;
}

// TAG-norm D=8 gather, dual streams; all operands contiguous [N][8]
__global__ void k_g8_dual(
    const float* __restrict__ ha, const float* __restrict__ adda,
    const float* __restrict__ biasa, int acta,
    const float* __restrict__ hb, const float* __restrict__ addb,
    const float* __restrict__ biasb, int actb,
    const int* __restrict__ perm, const int* __restrict__ off,
    const int* __restrict__ srcarr, const float* __restrict__ dis,
    float* __restrict__ outa, float* __restrict__ outb) {
  int g = blockIdx.x * 128 + (threadIdx.x >> 1);
  int t = threadIdx.x & 1;
  if (g >= NN) return;
  int node = perm[g];
  int s = off[node], e = off[node + 1];
  const float4* ha4 = (const float4*)ha;
  const float4* hb4 = (const float4*)hb;
  float4 accA = {0, 0, 0, 0}, accB = {0, 0, 0, 0};
  int p = s;
  for (; p + 2 <= e; p += 2) {
    int s0 = srcarr[p], s1 = srcarr[p + 1];
    float d0 = dis[s0], d1 = dis[s1];
    float4 a0 = ha4[(long)s0 * 2 + t], a1 = ha4[(long)s1 * 2 + t];
    float4 b0 = hb4[(long)s0 * 2 + t], b1 = hb4[(long)s1 * 2 + t];
    accA = f4fma(d0, a0, accA); accA = f4fma(d1, a1, accA);
    accB = f4fma(d0, b0, accB); accB = f4fma(d1, b1, accB);
  }
  if (p < e) {
    int s0 = srcarr[p];
    float d0 = dis[s0];
    accA = f4fma(d0, ha4[(long)s0 * 2 + t], accA);
    accB = f4fma(d0, hb4[(long)s0 * 2 + t], accB);
  }
  float dn = dis[node];
  float4 rA = f4scale(accA, dn);
  rA = f4add(rA, ((const float4*)adda)[(long)node * 2 + t]);
  if (biasa) rA = f4add(rA, ((const float4*)biasa)[t]);
  ((float4*)outa)[(long)node * 2 + t] = act4(rA, acta);
  float4 rB = f4scale(accB, dn);
  rB = f4add(rB, ((const float4*)addb)[(long)node * 2 + t]);
  if (biasb) rB = f4add(rB, ((const float4*)biasb)[t]);
  ((float4*)outb)[(long)node * 2 + t] = act4(rB, actb);
}

__global__ void k_g8_single(
    const float* __restrict__ ha, const float* __restrict__ adda,
    const float* __restrict__ biasa, int acta,
    const int* __restrict__ perm, const int* __restrict__ off,
    const int* __restrict__ srcarr, const float* __restrict__ dis,
    float* __restrict__ outa) {
  int g = blockIdx.x * 128 + (threadIdx.x >> 1);
  int t = threadIdx.x & 1;
  if (g >= NN) return;
  int node = perm[g];
  int s = off[node], e = off[node + 1];
  const float4* ha4 = (const float4*)ha;
  float4 accA = {0, 0, 0, 0};
  int p = s;
  for (; p + 4 <= e; p += 4) {
    int s0 = srcarr[p], s1 = srcarr[p + 1], s2 = srcarr[p + 2], s3 = srcarr[p + 3];
    float d0 = dis[s0], d1 = dis[s1], d2 = dis[s2], d3 = dis[s3];
    accA = f4fma(d0, ha4[(long)s0 * 2 + t], accA);
    accA = f4fma(d1, ha4[(long)s1 * 2 + t], accA);
    accA = f4fma(d2, ha4[(long)s2 * 2 + t], accA);
    accA = f4fma(d3, ha4[(long)s3 * 2 + t], accA);
  }
  for (; p < e; ++p) {
    int s0 = srcarr[p];
    accA = f4fma(dis[s0], ha4[(long)s0 * 2 + t], accA);
  }
  float4 rA = f4scale(accA, dis[node]);
  rA = f4add(rA, ((const float4*)adda)[(long)node * 2 + t]);
  if (biasa) rA = f4add(rA, ((const float4*)biasa)[t]);
  ((float4*)outa)[(long)node * 2 + t] = act4(rA, acta);
}

// 1-dim gathers: G=4 lanes per node, shuffle reduce. MODE 0 = SAGE mean, 1 = TAG norm.
template<int MODE>
__global__ void k_g1_dual(
    const float* __restrict__ ua, const float* __restrict__ adda,
    const float* __restrict__ biasa, int acta,
    const float* __restrict__ ub, const float* __restrict__ addb,
    const float* __restrict__ biasb, int actb,
    const int* __restrict__ perm, const int* __restrict__ off,
    const int* __restrict__ srcarr, const float* __restrict__ dis,
    float* __restrict__ outa, float* __restrict__ outb) {
  int g = blockIdx.x * 64 + (threadIdx.x >> 2);
  int t = threadIdx.x & 3;
  if (g >= NN) return;
  int node = perm[g];
  int s = off[node], e = off[node + 1];
  float accA = 0.0f, accB = 0.0f;
  for (int p = s + t; p < e; p += 4) {
    int s0 = srcarr[p];
    float d = (MODE == 1) ? dis[s0] : 1.0f;
    accA += d * ua[s0];
    accB += d * ub[s0];
  }
  accA += __shfl_xor(accA, 1, 64); accA += __shfl_xor(accA, 2, 64);
  accB += __shfl_xor(accB, 1, 64); accB += __shfl_xor(accB, 2, 64);
  if (t == 0) {
    float sc;
    if (MODE == 0) { int c = e - s; sc = 1.0f / (float)(c > 0 ? c : 1); }
    else sc = dis[node];
    float rA = accA * sc + adda[node];
    if (biasa) rA += biasa[0];
    outa[node] = act_apply(rA, acta);
    float rB = accB * sc + addb[node];
    if (biasb) rB += biasb[0];
    outb[node] = act_apply(rB, actb);
  }
}

template<int MODE>
__global__ void k_g1_single(
    const float* __restrict__ ua, const float* __restrict__ adda,
    const float* __restrict__ biasa, int acta,
    const int* __restrict__ perm, const int* __restrict__ off,
    const int* __restrict__ srcarr, const float* __restrict__ dis,
    float* __restrict__ outa) {
  int g = blockIdx.x * 64 + (threadIdx.x >> 2);
  int t = threadIdx.x & 3;
  if (g >= NN) return;
  int node = perm[g];
  int s = off[node], e = off[node + 1];
  float accA = 0.0f;
  for (int p = s + t; p < e; p += 4) {
    int s0 = srcarr[p];
    float d = (MODE == 1) ? dis[s0] : 1.0f;
    accA += d * ua[s0];
  }
  accA += __shfl_xor(accA, 1, 64); accA += __shfl_xor(accA, 2, 64);
  if (t == 0) {
    float sc;
    if (MODE == 0) { int c = e - s; sc = 1.0f / (float)(c > 0 ? c : 1); }
    else sc = dis[node];
    float rA = accA * sc + adda[node];
    if (biasa) rA += biasa[0];
    outa[node] = act_apply(rA, acta);
  }
}

// last chain-b 1-dim hop fused with final linear+relu
__global__ void k_g1_final(
    const float* __restrict__ ua, const float* __restrict__ adda,
    const float* __restrict__ biasa,
    const float* __restrict__ x1s, const float* __restrict__ x2s,
    const float* __restrict__ lw, const float* __restrict__ lb,
    const int* __restrict__ perm, const int* __restrict__ off,
    const int* __restrict__ srcarr, const float* __restrict__ dis,
    float* __restrict__ out) {
  int g = blockIdx.x * 64 + (threadIdx.x >> 2);
  int t = threadIdx.x & 3;
  if (g >= NN) return;
  int node = perm[g];
  int s = off[node], e = off[node + 1];
  float accA = 0.0f;
  for (int p = s + t; p < e; p += 4) {
    int s0 = srcarr[p];
    accA += dis[s0] * ua[s0];
  }
  accA += __shfl_xor(accA, 1, 64); accA += __shfl_xor(accA, 2, 64);
  if (t == 0) {
    float x3v = fmaxf(accA * dis[node] + adda[node] + biasa[0], 0.0f);
    float v = x1s[node] * lw[0] + x2s[node] * lw[1] + x3v * lw[2] + lb[0];
    out[node] = fmaxf(v, 0.0f);
  }
}

// ---------------- SAGE layer-1 fused GEMM (small K), fp16 output ----------------
template<int K1, int K2>
__global__ __launch_bounds__(256) void k_sage_mm(
    const float* __restrict__ A1, int as1, const float* __restrict__ A2, int as2,
    const float* __restrict__ W1, const float* __restrict__ W2,
    const float* __restrict__ bias, __half* __restrict__ out, int act) {
  constexpr int K = K1 + K2;
  constexpr int BM = 64;
  constexpr int BK = 32;
  __shared__ float Ash[BK][BM];
  __shared__ float Wsh[BK][128];
  int m0 = blockIdx.x * BM;
  int tid = threadIdx.x;
  int tx = tid & 15, ty = tid >> 4;
  int tm = ty * 4;
  int to = tx * 8;
  float acc[4][8] = {};
  for (int k0 = 0; k0 < K; k0 += BK) {
    {
      int mm = tid % BM, kb = tid / BM;
      #pragma unroll
      for (int it = 0; it < BK / 4; ++it) {
        int kk = kb + 4 * it;
        int gk = k0 + kk, gm = m0 + mm;
        float v = 0.0f;
        if (gm < NN && gk < K)
          v = (gk < K1) ? A1[(long)gm * as1 + gk] : A2[(long)gm * as2 + (gk - K1)];
        Ash[kk][mm] = v;
      }
    }
    {
      int oo = tid % 128, kb = tid / 128;
      #pragma unroll
      for (int it = 0; it < BK / 2; ++it) {
        int kk = kb + 2 * it;
        int gk = k0 + kk;
        float v = 0.0f;
        if (gk < K)
          v = (gk < K1) ? W1[oo * K1 + gk] : W2[oo * K2 + (gk - K1)];
        Wsh[kk][oo] = v;
      }
    }
    __syncthreads();
    #pragma unroll
    for (int kk = 0; kk < BK; ++kk) {
      float4 av = *reinterpret_cast<const float4*>(&Ash[kk][tm]);
      float4 wv0 = *reinterpret_cast<const float4*>(&Wsh[kk][to]);
      float4 wv1 = *reinterpret_cast<const float4*>(&Wsh[kk][to + 4]);
      float a[4] = {av.x, av.y, av.z, av.w};
      float w[8] = {wv0.x, wv0.y, wv0.z, wv0.w, wv1.x, wv1.y, wv1.z, wv1.w};
      #pragma unroll
      for (int i2 = 0; i2 < 4; ++i2)
        #pragma unroll
        for (int j = 0; j < 8; ++j)
          acc[i2][j] += a[i2] * w[j];
    }
    __syncthreads();
  }
  #pragma unroll
  for (int i2 = 0; i2 < 4; ++i2) {
    int gm = m0 + tm + i2;
    if (gm >= NN) continue;
    __half2* orow = (__half2*)(out + (long)gm * 128);
    #pragma unroll
    for (int j = 0; j < 4; ++j) {
      float lo = act_apply(acc[i2][2 * j] + bias[to + 2 * j], act);
      float hi = act_apply(acc[i2][2 * j + 1] + bias[to + 2 * j + 1], act);
      orow[to / 2 + j] = __floats2half2_rn(lo, hi);
    }
  }
}

// ---------------- SAGE layer-2 via MFMA fp16, fused sigmoid + proj2 epilogue ----------------
// A = [mean128_h || x1a_h] (K=256), W = w2h [128][256]. Writes pp, qq only.
// MFMA 16x16x32_f16 fragments: A lane l: row=l&15, k=(l>>4)*8+j (8 contiguous halves).
// B lane l: col=l&15, same k pattern (W[o][k] row-major = B^T, contiguous in k).
// C/D: col=l&15, row=(l>>4)*4+reg  [verified m89, dtype-independent].
__global__ __launch_bounds__(256) void k_mm2_mfma(
    const __half* __restrict__ A1, const __half* __restrict__ A2,
    const __half* __restrict__ W, const float* __restrict__ bias,
    const float* __restrict__ w3l, const float* __restrict__ w3r,
    float* __restrict__ pp, float* __restrict__ qq) {
  int tid = threadIdx.x;
  int wave = tid >> 6;
  int l = tid & 63;
  int lr = l & 15;
  int lk = l >> 4;
  int m0 = blockIdx.x * 128 + wave * 32;
  f4v acc[2][8] = {};
  #pragma unroll
  for (int ks = 0; ks < 8; ++ks) {
    const __half* Asrc = (ks < 4) ? A1 : A2;
    int kk = (ks & 3) * 32 + lk * 8;
    h8v afrag[2];
    #pragma unroll
    for (int rt = 0; rt < 2; ++rt) {
      int row = m0 + rt * 16 + lr;
      h8v z = {};
      afrag[rt] = (row < NN) ? *(const h8v*)&Asrc[(long)row * 128 + kk] : z;
    }
    #pragma unroll
    for (int c = 0; c < 8; ++c) {
      h8v bfrag = *(const h8v*)&W[(long)(c * 16 + lr) * 256 + ks * 32 + lk * 8];
      acc[0][c] = __builtin_amdgcn_mfma_f32_16x16x32_f16(afrag[0], bfrag, acc[0][c], 0, 0, 0);
      acc[1][c] = __builtin_amdgcn_mfma_f32_16x16x32_f16(afrag[1], bfrag, acc[1][c], 0, 0, 0);
    }
  }
  // epilogue: sigmoid + dual 128-dot projection, 16-lane tree reduce
  float wl[8], wr[8], bi[8];
  #pragma unroll
  for (int c = 0; c < 8; ++c) {
    wl[c] = w3l[c * 16 + lr];
    wr[c] = w3r[c * 16 + lr];
    bi[c] = bias[c * 16 + lr];
  }
  #pragma unroll
  for (int rt = 0; rt < 2; ++rt) {
    #pragma unroll
    for (int reg = 0; reg < 4; ++reg) {
      float s1 = 0.0f, s2 = 0.0f;
      #pragma unroll
      for (int c = 0; c < 8; ++c) {
        float v = acc[rt][c][reg] + bi[c];
        float sg = 1.0f / (1.0f + expf(-v));
        s1 += sg * wl[c];
        s2 += sg * wr[c];
      }
      #pragma unroll
      for (int d = 1; d < 16; d <<= 1) {
        s1 += __shfl_xor(s1, d, 64);
        s2 += __shfl_xor(s2, d, 64);
      }
      int row = m0 + rt * 16 + lk * 4 + reg;
      if (lr == 0 && row < NN) { pp[row] = s1; qq[row] = s2; }
    }
  }
}

// ---------------- TAG P-precompute, hop-major output [NH][N][NO] ----------------
template<int KIN, int NH, int NO>
__global__ void k_tagP(const float* __restrict__ A, int as,
                       const float* __restrict__ w, float* __restrict__ out) {
  int i = blockIdx.x * blockDim.x + threadIdx.x;
  if (i >= NN) return;
  float a[KIN];
  #pragma unroll
  for (int j = 0; j < KIN; ++j) a[j] = A[(long)i * as + j];
  #pragma unroll
  for (int k = 0; k < NH; ++k) {
    #pragma unroll
    for (int o = 0; o < NO; ++o) {
      float s = 0.0f;
      #pragma unroll
      for (int j = 0; j < KIN; ++j) s += a[j] * w[o * (KIN * NH) + k * KIN + j];
      out[((long)k * NN + i) * NO + o] = s;
    }
  }
}

extern "C" void kernel_launch(void* const* d_in, const int* in_sizes, int n_in,
                              void* d_out, int out_size, void* d_ws, size_t ws_size,
                              hipStream_t stream) {
  const float* x    = (const float*)d_in[0];
  const int*   ei   = (const int*)d_in[1];
  const float* s1wl = (const float*)d_in[2];
  const float* s1wr = (const float*)d_in[3];
  const float* s1b  = (const float*)d_in[4];
  const float* s2wl = (const float*)d_in[5];
  const float* s2wr = (const float*)d_in[6];
  const float* s2b  = (const float*)d_in[7];
  const float* s3wl = (const float*)d_in[8];
  const float* s3wr = (const float*)d_in[9];
  const float* s3b  = (const float*)d_in[10];
  const float* t1aw = (const float*)d_in[11];
  const float* t1ab = (const float*)d_in[12];
  const float* t2aw = (const float*)d_in[13];
  const float* t2ab = (const float*)d_in[14];
  const float* t1bw = (const float*)d_in[15];
  const float* t1bb = (const float*)d_in[16];
  const float* t2bw = (const float*)d_in[17];
  const float* t2bb = (const float*)d_in[18];
  const float* lw   = (const float*)d_in[19];
  const float* lb   = (const float*)d_in[20];
  float* out = (float*)d_out;

  char* basep = (char*)d_ws;
  size_t off = 0;
  auto alloc = [&](size_t bytes) -> void* {
    void* ptr = basep + off;
    off = (off + bytes + 255) & ~(size_t)255;
    return ptr;
  };
  int*   cnt     = (int*)alloc((size_t)NN * 4);
  int*   csr_off = (int*)alloc((size_t)(NN + 1) * 4);
  int*   cursor  = (int*)alloc((size_t)NN * 4);
  float* dis     = (float*)alloc((size_t)NN * 4);
  int*   csr_src = (int*)alloc((size_t)EE * 4);
  int*   perm    = (int*)alloc((size_t)NN * 4);
  int*   bsum    = (int*)alloc(128 * 4);
  int*   bexcl   = (int*)alloc(128 * 4);
  int*   hist    = (int*)alloc(NBIN * 4);
  int*   bincur  = (int*)alloc(NBIN * 4);
  float* x1s     = (float*)alloc((size_t)NN * 4);
  float* x2s     = (float*)alloc((size_t)NN * 4);
  float* pp      = (float*)alloc((size_t)NN * 4);
  float* qq      = (float*)alloc((size_t)NN * 4);
  float* uA1     = (float*)alloc((size_t)NN * 4);
  float* uA2     = (float*)alloc((size_t)NN * 4);
  float* uB1     = (float*)alloc((size_t)NN * 4);
  float* uB2     = (float*)alloc((size_t)NN * 4);
  float* x12     = (float*)alloc((size_t)NN * 12 * 4);
  float* mean12  = (float*)alloc((size_t)NN * 12 * 4);
  __half* w2h    = (__half*)alloc((size_t)128 * 256 * 2);
  __half* x1a_h  = (__half*)alloc((size_t)NN * 128 * 2);   // region1 overlay after mm2
  __half* mean128_h = (__half*)alloc((size_t)NN * 128 * 2);
  float* region2 = (float*)alloc((size_t)NN * 87 * 4);

  // Region 1 overlay (x1a_h = 64N float-equivalents; reused after k_mm2_mfma):
  float* r1 = (float*)x1a_h;
  float* Pa  = r1;                      // [4][N][8]  = 32N floats
  float* zaA = r1 + (size_t)NN * 32;    // [N][8]
  float* zbA = r1 + (size_t)NN * 40;    // [N][8]
  float* x2a = r1 + (size_t)NN * 48;    // [N][8]
  float* P2  = r1 + (size_t)NN * 56;    // [4][N]  (60N total <= 64N ok)
  // Region 2 (independent alloc, 87N floats):
  float* Pb  = region2;                      // [7][N][8] = 56N
  float* zaB = region2 + (size_t)NN * 56;    // [N][8]
  float* zbB = region2 + (size_t)NN * 64;    // [N][8]
  float* x3a = region2 + (size_t)NN * 72;    // [N][8]
  float* P2b = region2 + (size_t)NN * 80;    // [7][N]

  // ---- CSR build ----
  hipMemsetAsync(cnt, 0, (size_t)NN * 4, stream);
  k_count<<<(EE + 255) / 256, 256, 0, stream>>>(ei, cnt);
  k_bsum<<<NB, 1024, 0, stream>>>(cnt, bsum);
  k_bscan<<<1, 128, 0, stream>>>(bsum, bexcl);
  k_bapply<<<NB, 1024, 0, stream>>>(cnt, bexcl, csr_off, cursor, dis);
  k_fill<<<(EE + 255) / 256, 256, 0, stream>>>(ei, cursor, csr_src);

  // ---- degree sort ----
  hipMemsetAsync(hist, 0, NBIN * 4, stream);
  k_hist<<<(NN + 255) / 256, 256, 0, stream>>>(cnt, hist);
  k_binscan<<<1, 64, 0, stream>>>(hist, bincur);
  k_scatter<<<(NN + 255) / 256, 256, 0, stream>>>(cnt, bincur, perm);

  // ---- weight cast for MFMA ----
  k_wcast<<<128, 256, 0, stream>>>(s2wl, s2wr, w2h);

  // ---- SAGE chain ----
  k_pad12<<<(NN * 12 + 255) / 256, 256, 0, stream>>>(x, x12);
  k_gmean12<<<(NN + 63) / 64, 256, 0, stream>>>(x12, perm, csr_off, csr_src, mean12);
  k_sage_mm<11, 11><<<(NN + 63) / 64, 256, 0, stream>>>(mean12, 12, x, 11, s1wl, s1wr, s1b, x1a_h, 1);
  k_gather128<<<(NN + 15) / 16, 256, 0, stream>>>(x1a_h, perm, csr_off, csr_src, mean128_h);
  k_mm2_mfma<<<(NN + 127) / 128, 256, 0, stream>>>(mean128_h, x1a_h, w2h, s2b, s3wl, s3wr, pp, qq);
  k_g1_single<0><<<(NN + 63) / 64, 256, 0, stream>>>(
      pp, qq, s3b, 2, perm, csr_off, csr_src, dis, x1s);

  // ---- TAG P precompute (after k_mm2_mfma frees region1) ----
  k_tagP<11, 4, 8><<<(NN + 255) / 256, 256, 0, stream>>>(x, 11, t1aw, Pa);
  k_tagP<11, 7, 8><<<(NN + 255) / 256, 256, 0, stream>>>(x, 11, t1bw, Pb);

  const size_t S8 = (size_t)NN * 8;
  // ---- fused D=8 hops (chain a: 3 hops; chain b: 6 hops) ----
  k_g8_dual<<<(NN + 127) / 128, 256, 0, stream>>>(
      Pa + 3 * S8, Pa + 2 * S8, nullptr, 0,
      Pb + 6 * S8, Pb + 5 * S8, nullptr, 0,
      perm, csr_off, csr_src, dis, zaA, zaB);
  k_g8_dual<<<(NN + 127) / 128, 256, 0, stream>>>(
      zaA, Pa + 1 * S8, nullptr, 0,
      zaB, Pb + 4 * S8, nullptr, 0,
      perm, csr_off, csr_src, dis, zbA, zbB);
  k_g8_dual<<<(NN + 127) / 128, 256, 0, stream>>>(
      zbA, Pa, t1ab, 1,
      zbB, Pb + 3 * S8, nullptr, 0,
      perm, csr_off, csr_src, dis, x2a, zaB);
  k_g8_single<<<(NN + 127) / 128, 256, 0, stream>>>(
      zaB, Pb + 2 * S8, nullptr, 0, perm, csr_off, csr_src, dis, zbB);
  k_g8_single<<<(NN + 127) / 128, 256, 0, stream>>>(
      zbB, Pb + 1 * S8, nullptr, 0, perm, csr_off, csr_src, dis, zaB);
  k_g8_single<<<(NN + 127) / 128, 256, 0, stream>>>(
      zaB, Pb, t1bb, 1, perm, csr_off, csr_src, dis, x3a);

  // ---- second TAG linears (hop-major [NH][N]) ----
  k_tagP<8, 4, 1><<<(NN + 255) / 256, 256, 0, stream>>>(x2a, 8, t2aw, P2);
  k_tagP<8, 7, 1><<<(NN + 255) / 256, 256, 0, stream>>>(x3a, 8, t2bw, P2b);

  // ---- fused 1-dim hops ----
  k_g1_dual<1><<<(NN + 63) / 64, 256, 0, stream>>>(
      P2 + 3 * (size_t)NN, P2 + 2 * (size_t)NN, nullptr, 0,
      P2b + 6 * (size_t)NN, P2b + 5 * (size_t)NN, nullptr, 0,
      perm, csr_off, csr_src, dis, uA1, uB1);
  k_g1_dual<1><<<(NN + 63) / 64, 256, 0, stream>>>(
      uA1, P2 + 1 * (size_t)NN, nullptr, 0,
      uB1, P2b + 4 * (size_t)NN, nullptr, 0,
      perm, csr_off, csr_src, dis, uA2, uB2);
  k_g1_dual<1><<<(NN + 63) / 64, 256, 0, stream>>>(
      uA2, P2, t2ab, 2,
      uB2, P2b + 3 * (size_t)NN, nullptr, 0,
      perm, csr_off, csr_src, dis, x2s, uB1);
  k_g1_single<1><<<(NN + 63) / 64, 256, 0, stream>>>(
      uB1, P2b + 2 * (size_t)NN, nullptr, 0, perm, csr_off, csr_src, dis, uB2);
  k_g1_single<1><<<(NN + 63) / 64, 256, 0, stream>>>(
      uB2, P2b + 1 * (size_t)NN, nullptr, 0, perm, csr_off, csr_src, dis, uB1);
  // last hop fused with final combine
  k_g1_final<<<(NN + 63) / 64, 256, 0, stream>>>(
      uB1, P2b, t2bb, x1s, x2s, lw, lb, perm, csr_off, csr_src, dis, out);
}

// Round 5
// 611.739 us; speedup vs baseline: 2.6355x; 1.4715x over previous
//
#include <hip/hip_runtime.h>
#include <hip/hip_bf16.h>
#include <hip/hip_fp16.h>

#define NN 100000
#define EE 1600000
#define NBIN 64
#define BSH 9
#define BSZ 512
#define NBK 196   // ceil(NN/512)

typedef _Float16 h8v __attribute__((ext_vector_type(8)));
typedef float f4v __attribute__((ext_vector_type(4)));

__device__ __forceinline__ float act_apply(float v, int act) {
  if (act == 1) return 1.0f / (1.0f + expf(-v));
  if (act == 2) return fmaxf(v, 0.0f);
  return v;
}
__device__ __forceinline__ float4 f4fma(float s, float4 v, float4 a) {
  a.x += s * v.x; a.y += s * v.y; a.z += s * v.z; a.w += s * v.w; return a;
}
__device__ __forceinline__ float4 f4add(float4 a, float4 b) {
  a.x += b.x; a.y += b.y; a.z += b.z; a.w += b.w; return a;
}
__device__ __forceinline__ float4 f4scale(float4 a, float s) {
  a.x *= s; a.y *= s; a.z *= s; a.w *= s; return a;
}
__device__ __forceinline__ float4 h4f(uint2 v) {
  __half2 a = *reinterpret_cast<__half2*>(&v.x);
  __half2 b = *reinterpret_cast<__half2*>(&v.y);
  float2 fa = __half22float2(a), fb = __half22float2(b);
  return make_float4(fa.x, fa.y, fb.x, fb.y);
}
__device__ __forceinline__ void h8acc(uint4 v, float* a) {
  float4 lo = h4f(make_uint2(v.x, v.y));
  float4 hi = h4f(make_uint2(v.z, v.w));
  a[0] += lo.x; a[1] += lo.y; a[2] += lo.z; a[3] += lo.w;
  a[4] += hi.x; a[5] += hi.y; a[6] += hi.z; a[7] += hi.w;
}
__device__ __forceinline__ uint2 pack4h(float4 r) {
  __half2 q0 = __floats2half2_rn(r.x, r.y), q1 = __floats2half2_rn(r.z, r.w);
  uint2 o; o.x = *(unsigned*)&q0; o.y = *(unsigned*)&q1; return o;
}

// ================= CSR build (bucketed, XCD-local writes) =================
// 1) 196-bin bucket histogram of dst
__global__ __launch_bounds__(256) void k_bhist(const int* __restrict__ ei, int* __restrict__ ghist) {
  __shared__ int lh[NBK];
  for (int j = threadIdx.x; j < NBK; j += 256) lh[j] = 0;
  __syncthreads();
  for (int i = blockIdx.x * 256 + threadIdx.x; i < EE; i += gridDim.x * 256)
    atomicAdd(&lh[ei[EE + i] >> BSH], 1);
  __syncthreads();
  for (int j = threadIdx.x; j < NBK; j += 256) {
    int v = lh[j];
    if (v) atomicAdd(&ghist[j], v);
  }
}

// 2) scan bucket counts -> gcur (split cursors) + bexclB (region bounds)
__global__ void k_b196scan(const int* __restrict__ ghist, int* __restrict__ gcur,
                           int* __restrict__ bexclB, int* __restrict__ csr_off) {
  __shared__ int sh[256];
  int tid = threadIdx.x;
  int v = (tid < NBK) ? ghist[tid] : 0;
  sh[tid] = v;
  __syncthreads();
  for (int d = 1; d < 256; d <<= 1) {
    int t = (tid >= d) ? sh[tid - d] : 0;
    __syncthreads();
    sh[tid] += t;
    __syncthreads();
  }
  int excl = sh[tid] - v;
  if (tid < NBK) { gcur[tid] = excl; bexclB[tid] = excl; }
  if (tid == 0) { bexclB[NBK] = EE; csr_off[NN] = EE; }
}

// 3) WG-local 196-way multi-split of (src,dst) pairs, coalesced flush
__global__ __launch_bounds__(256) void k_split(const int* __restrict__ ei,
                                               int* __restrict__ gcur,
                                               uint2* __restrict__ pairs) {
  __shared__ int cntL[256];
  __shared__ int segO[256];
  __shared__ int curL[256];
  __shared__ int baseL[256];
  __shared__ uint2 stag[4096];
  int tid = threadIdx.x;
  int tile0 = blockIdx.x * 4096;
  int tcnt = min(4096, EE - tile0);
  cntL[tid] = 0; curL[tid] = 0;
  __syncthreads();
  for (int i = tid; i < tcnt; i += 256)
    atomicAdd(&cntL[ei[EE + tile0 + i] >> BSH], 1);
  __syncthreads();
  int v = cntL[tid];
  segO[tid] = v;
  __syncthreads();
  for (int d = 1; d < 256; d <<= 1) {
    int t = (tid >= d) ? segO[tid - d] : 0;
    __syncthreads();
    segO[tid] += t;
    __syncthreads();
  }
  int excl = segO[tid] - v;
  __syncthreads();
  segO[tid] = excl;
  __syncthreads();
  for (int i = tid; i < tcnt; i += 256) {
    int s = ei[tile0 + i], dd = ei[EE + tile0 + i];
    int b = dd >> BSH;
    int slot = segO[b] + atomicAdd(&curL[b], 1);
    stag[slot] = make_uint2((unsigned)s, (unsigned)dd);
  }
  baseL[tid] = v ? atomicAdd(&gcur[tid], v) : 0;
  __syncthreads();
  for (int i = tid; i < tcnt; i += 256) {
    uint2 pr = stag[i];
    int b = (int)(pr.y >> BSH);
    pairs[baseL[b] + (i - segO[b])] = pr;
  }
}

// 4) per-bucket count + in-bucket scan -> cnt, csr_off, dis (dense writes, no global atomics)
__global__ __launch_bounds__(256) void k_bcount(const uint2* __restrict__ pairs,
                                                const int* __restrict__ bexclB,
                                                int* __restrict__ cnt, int* __restrict__ csr_off,
                                                float* __restrict__ dis) {
  __shared__ int c[BSZ];
  __shared__ int ps[256];
  int tid = threadIdx.x;
  int b = blockIdx.x;
  int lo = b << BSH;
  for (int j = tid; j < BSZ; j += 256) c[j] = 0;
  __syncthreads();
  int s0e = bexclB[b], s1e = bexclB[b + 1];
  for (int i = s0e + tid; i < s1e; i += 256)
    atomicAdd(&c[pairs[i].y - lo], 1);
  __syncthreads();
  int a0 = c[2 * tid], a1 = c[2 * tid + 1];
  int pv = a0 + a1;
  ps[tid] = pv;
  __syncthreads();
  for (int d = 1; d < 256; d <<= 1) {
    int t = (tid >= d) ? ps[tid - d] : 0;
    __syncthreads();
    ps[tid] += t;
    __syncthreads();
  }
  int pex = ps[tid] - pv;
  int base = s0e + pex;
  int n0 = lo + 2 * tid, n1 = n0 + 1;
  if (n0 < NN) {
    csr_off[n0] = base; cnt[n0] = a0;
    dis[n0] = (a0 > 0) ? rsqrtf((float)a0) : 0.0f;
  }
  if (n1 < NN) {
    csr_off[n1] = base + a0; cnt[n1] = a1;
    dis[n1] = (a1 > 0) ? rsqrtf((float)a1) : 0.0f;
  }
}

// 5) per-bucket fill: LDS cursors, bucket-local scatter (single-XCD window)
__global__ __launch_bounds__(256) void k_bfill(const uint2* __restrict__ pairs,
                                               const int* __restrict__ bexclB,
                                               const int* __restrict__ csr_off,
                                               int* __restrict__ csr_src) {
  __shared__ int cur[BSZ];
  int tid = threadIdx.x;
  int b = blockIdx.x;
  int lo = b << BSH;
  for (int j = tid; j < BSZ; j += 256) {
    int n = lo + j;
    cur[j] = (n < NN) ? csr_off[n] : 0;
  }
  __syncthreads();
  int s0e = bexclB[b], s1e = bexclB[b + 1];
  for (int i = s0e + tid; i < s1e; i += 256) {
    uint2 pr = pairs[i];
    int p = atomicAdd(&cur[pr.y - lo], 1);
    csr_src[p] = (int)pr.x;
  }
}

// ================= degree sort (perm) =================
__global__ __launch_bounds__(256) void k_hist(const int* __restrict__ cnt, int* __restrict__ hist) {
  __shared__ int lh[NBIN];
  if (threadIdx.x < NBIN) lh[threadIdx.x] = 0;
  __syncthreads();
  int i = blockIdx.x * 256 + threadIdx.x;
  if (i < NN) atomicAdd(&lh[min(cnt[i], NBIN - 1)], 1);
  __syncthreads();
  if (threadIdx.x < NBIN) {
    int v = lh[threadIdx.x];
    if (v) atomicAdd(&hist[threadIdx.x], v);
  }
}
__global__ void k_binscan(const int* __restrict__ hist, int* __restrict__ bincur) {
  int tid = threadIdx.x;
  int v = hist[tid];
  int incl = v;
  for (int d = 1; d < 64; d <<= 1) {
    int t = __shfl_up(incl, d, 64);
    if (tid >= d) incl += t;
  }
  bincur[tid] = incl - v;
}
__global__ __launch_bounds__(256) void k_scatter(const int* __restrict__ cnt,
                                                 int* __restrict__ bincur,
                                                 int* __restrict__ perm) {
  __shared__ int lh[NBIN];
  __shared__ int lbase[NBIN];
  if (threadIdx.x < NBIN) lh[threadIdx.x] = 0;
  __syncthreads();
  int i = blockIdx.x * 256 + threadIdx.x;
  int b = 0, r = 0;
  bool valid = i < NN;
  if (valid) {
    b = min(cnt[i], NBIN - 1);
    r = atomicAdd(&lh[b], 1);
  }
  __syncthreads();
  if (threadIdx.x < NBIN) {
    int v = lh[threadIdx.x];
    lbase[threadIdx.x] = v ? atomicAdd(&bincur[threadIdx.x], v) : 0;
  }
  __syncthreads();
  if (valid) perm[lbase[b] + r] = i;
}

// ================= feature prep =================
__global__ void k_pad12h(const float* __restrict__ x, __half* __restrict__ x12h) {
  int i = blockIdx.x * blockDim.x + threadIdx.x;
  if (i >= NN * 12) return;
  int n = i / 12, j = i - n * 12;
  x12h[i] = __float2half((j < 11) ? x[n * 11 + j] : 0.0f);
}

__global__ void k_wcast(const float* __restrict__ wl, const float* __restrict__ wr,
                        __half* __restrict__ w2h) {
  int i = blockIdx.x * 256 + threadIdx.x;
  if (i >= 128 * 256) return;
  int o = i >> 8, k = i & 255;
  float v = (k < 128) ? wl[o * 128 + k] : wr[o * 128 + (k - 128)];
  w2h[i] = __float2half(v);
}

// ================= gathers =================
// SAGE mean, D=12 fp16 in / f32 out, G=4 (t<3), 8B/lane
__global__ void k_gmean12h(const __half* __restrict__ x12h, const int* __restrict__ perm,
                           const int* __restrict__ off, const int* __restrict__ srcarr,
                           float* __restrict__ out) {
  int g = blockIdx.x * 64 + (threadIdx.x >> 2);
  int t = threadIdx.x & 3;
  if (g >= NN || t >= 3) return;
  int node = perm[g];
  int s = off[node], e = off[node + 1];
  const uint2* h2 = (const uint2*)x12h;   // 4 halves each; node stride 3
  float4 acc = {0, 0, 0, 0};
  int p = s;
  for (; p + 4 <= e; p += 4) {
    int s0 = srcarr[p], s1 = srcarr[p + 1], s2 = srcarr[p + 2], s3 = srcarr[p + 3];
    acc = f4add(acc, f4add(f4add(h4f(h2[(long)s0 * 3 + t]), h4f(h2[(long)s1 * 3 + t])),
                           f4add(h4f(h2[(long)s2 * 3 + t]), h4f(h2[(long)s3 * 3 + t]))));
  }
  for (; p < e; ++p) acc = f4add(acc, h4f(h2[(long)srcarr[p] * 3 + t]));
  int c = e - s;
  float inv = 1.0f / (float)(c > 0 ? c : 1);
  ((float4*)out)[(long)node * 3 + t] = f4scale(acc, inv);
}

// SAGE mean, D=128 fp16 in/out, G=16 lanes (uint4 = 8 halves)
__global__ void k_gather128(const __half* __restrict__ h, const int* __restrict__ perm,
                            const int* __restrict__ off, const int* __restrict__ srcarr,
                            __half* __restrict__ outh) {
  int g = blockIdx.x * 16 + (threadIdx.x >> 4);
  int t = threadIdx.x & 15;
  if (g >= NN) return;
  int node = perm[g];
  int s = off[node], e = off[node + 1];
  const uint4* h4 = (const uint4*)h;
  float acc[8] = {};
  int p = s;
  for (; p + 4 <= e; p += 4) {
    int s0 = srcarr[p], s1 = srcarr[p + 1], s2 = srcarr[p + 2], s3 = srcarr[p + 3];
    uint4 r0 = h4[(long)s0 * 16 + t], r1 = h4[(long)s1 * 16 + t];
    uint4 r2 = h4[(long)s2 * 16 + t], r3 = h4[(long)s3 * 16 + t];
    h8acc(r0, acc); h8acc(r1, acc); h8acc(r2, acc); h8acc(r3, acc);
  }
  for (; p < e; ++p) h8acc(h4[(long)srcarr[p] * 16 + t], acc);
  int c = e - s;
  float inv = 1.0f / (float)(c > 0 ? c : 1);
  uint4 o;
  __half2 p0 = __floats2half2_rn(acc[0] * inv, acc[1] * inv);
  __half2 p1 = __floats2half2_rn(acc[2] * inv, acc[3] * inv);
  __half2 p2 = __floats2half2_rn(acc[4] * inv, acc[5] * inv);
  __half2 p3 = __floats2half2_rn(acc[6] * inv, acc[7] * inv);
  o.x = *(unsigned*)&p0; o.y = *(unsigned*)&p1; o.z = *(unsigned*)&p2; o.w = *(unsigned*)&p3;
  ((uint4*)outh)[(long)node * 16 + t] = o;
}

// TAG D=8, fp16 pre-scaled streams (h stores dis_src*z). acts: 1=sig, 2=relu, 3=prescale-store
__global__ void k_g8h_dual(
    const __half* __restrict__ ha, const float* __restrict__ adda,
    const float* __restrict__ biasa, int acta,
    const __half* __restrict__ hb, const float* __restrict__ addb,
    const float* __restrict__ biasb, int actb,
    const int* __restrict__ perm, const int* __restrict__ off,
    const int* __restrict__ srcarr, const float* __restrict__ dis,
    __half* __restrict__ outa, __half* __restrict__ outb) {
  int g = blockIdx.x * 128 + (threadIdx.x >> 1);
  int t = threadIdx.x & 1;
  if (g >= NN) return;
  int node = perm[g];
  int s = off[node], e = off[node + 1];
  const uint2* ha2 = (const uint2*)ha;
  const uint2* hb2 = (const uint2*)hb;
  float4 accA = {0, 0, 0, 0}, accB = {0, 0, 0, 0};
  int p = s;
  for (; p + 4 <= e; p += 4) {
    int s0 = srcarr[p], s1 = srcarr[p + 1], s2 = srcarr[p + 2], s3 = srcarr[p + 3];
    accA = f4add(accA, f4add(f4add(h4f(ha2[(long)s0 * 2 + t]), h4f(ha2[(long)s1 * 2 + t])),
                             f4add(h4f(ha2[(long)s2 * 2 + t]), h4f(ha2[(long)s3 * 2 + t]))));
    accB = f4add(accB, f4add(f4add(h4f(hb2[(long)s0 * 2 + t]), h4f(hb2[(long)s1 * 2 + t])),
                             f4add(h4f(hb2[(long)s2 * 2 + t]), h4f(hb2[(long)s3 * 2 + t]))));
  }
  for (; p < e; ++p) {
    int s0 = srcarr[p];
    accA = f4add(accA, h4f(ha2[(long)s0 * 2 + t]));
    accB = f4add(accB, h4f(hb2[(long)s0 * 2 + t]));
  }
  float dn = dis[node];
  float4 rA = f4scale(accA, dn);
  rA = f4add(rA, ((const float4*)adda)[(long)node * 2 + t]);
  if (biasa) rA = f4add(rA, ((const float4*)biasa)[t]);
  if (acta == 1) { rA.x = act_apply(rA.x, 1); rA.y = act_apply(rA.y, 1); rA.z = act_apply(rA.z, 1); rA.w = act_apply(rA.w, 1); }
  else if (acta == 2) { rA.x = fmaxf(rA.x, 0.f); rA.y = fmaxf(rA.y, 0.f); rA.z = fmaxf(rA.z, 0.f); rA.w = fmaxf(rA.w, 0.f); }
  else if (acta == 3) rA = f4scale(rA, dn);
  ((uint2*)outa)[(long)node * 2 + t] = pack4h(rA);
  float4 rB = f4scale(accB, dn);
  rB = f4add(rB, ((const float4*)addb)[(long)node * 2 + t]);
  if (biasb) rB = f4add(rB, ((const float4*)biasb)[t]);
  if (actb == 1) { rB.x = act_apply(rB.x, 1); rB.y = act_apply(rB.y, 1); rB.z = act_apply(rB.z, 1); rB.w = act_apply(rB.w, 1); }
  else if (actb == 2) { rB.x = fmaxf(rB.x, 0.f); rB.y = fmaxf(rB.y, 0.f); rB.z = fmaxf(rB.z, 0.f); rB.w = fmaxf(rB.w, 0.f); }
  else if (actb == 3) rB = f4scale(rB, dn);
  ((uint2*)outb)[(long)node * 2 + t] = pack4h(rB);
}

__global__ void k_g8h_single(
    const __half* __restrict__ ha, const float* __restrict__ adda,
    const float* __restrict__ biasa, int acta,
    const int* __restrict__ perm, const int* __restrict__ off,
    const int* __restrict__ srcarr, const float* __restrict__ dis,
    __half* __restrict__ outa) {
  int g = blockIdx.x * 128 + (threadIdx.x >> 1);
  int t = threadIdx.x & 1;
  if (g >= NN) return;
  int node = perm[g];
  int s = off[node], e = off[node + 1];
  const uint2* ha2 = (const uint2*)ha;
  float4 accA = {0, 0, 0, 0};
  int p = s;
  for (; p + 4 <= e; p += 4) {
    int s0 = srcarr[p], s1 = srcarr[p + 1], s2 = srcarr[p + 2], s3 = srcarr[p + 3];
    accA = f4add(accA, f4add(f4add(h4f(ha2[(long)s0 * 2 + t]), h4f(ha2[(long)s1 * 2 + t])),
                             f4add(h4f(ha2[(long)s2 * 2 + t]), h4f(ha2[(long)s3 * 2 + t]))));
  }
  for (; p < e; ++p) accA = f4add(accA, h4f(ha2[(long)srcarr[p] * 2 + t]));
  float dn = dis[node];
  float4 rA = f4scale(accA, dn);
  rA = f4add(rA, ((const float4*)adda)[(long)node * 2 + t]);
  if (biasa) rA = f4add(rA, ((const float4*)biasa)[t]);
  if (acta == 1) { rA.x = act_apply(rA.x, 1); rA.y = act_apply(rA.y, 1); rA.z = act_apply(rA.z, 1); rA.w = act_apply(rA.w, 1); }
  else if (acta == 3) rA = f4scale(rA, dn);
  ((uint2*)outa)[(long)node * 2 + t] = pack4h(rA);
}

// D=1 gathers, pre-scaled f32 streams. MODE 0 = mean (SAGE), 1 = tag-norm.
// act: 0 none, 1 sig, 2 relu, 3 prescale-store (MODE1 only)
template<int MODE>
__global__ void k_g1_dual(
    const float* __restrict__ ua, const float* __restrict__ adda,
    const float* __restrict__ biasa, int acta,
    const float* __restrict__ ub, const float* __restrict__ addb,
    const float* __restrict__ biasb, int actb,
    const int* __restrict__ perm, const int* __restrict__ off,
    const int* __restrict__ srcarr, const float* __restrict__ dis,
    float* __restrict__ outa, float* __restrict__ outb) {
  int g = blockIdx.x * 64 + (threadIdx.x >> 2);
  int t = threadIdx.x & 3;
  if (g >= NN) return;
  int node = perm[g];
  int s = off[node], e = off[node + 1];
  float accA = 0.0f, accB = 0.0f;
  for (int p = s + t; p < e; p += 4) {
    int s0 = srcarr[p];
    accA += ua[s0];
    accB += ub[s0];
  }
  accA += __shfl_xor(accA, 1, 64); accA += __shfl_xor(accA, 2, 64);
  accB += __shfl_xor(accB, 1, 64); accB += __shfl_xor(accB, 2, 64);
  if (t == 0) {
    float sc;
    if (MODE == 0) { int c = e - s; sc = 1.0f / (float)(c > 0 ? c : 1); }
    else sc = dis[node];
    float rA = accA * sc + adda[node];
    if (biasa) rA += biasa[0];
    if (acta == 3) rA *= sc; else rA = act_apply(rA, acta);
    outa[node] = rA;
    float rB = accB * sc + addb[node];
    if (biasb) rB += biasb[0];
    if (actb == 3) rB *= sc; else rB = act_apply(rB, actb);
    outb[node] = rB;
  }
}

template<int MODE>
__global__ void k_g1_single(
    const float* __restrict__ ua, const float* __restrict__ adda,
    const float* __restrict__ biasa, int acta,
    const int* __restrict__ perm, const int* __restrict__ off,
    const int* __restrict__ srcarr, const float* __restrict__ dis,
    float* __restrict__ outa) {
  int g = blockIdx.x * 64 + (threadIdx.x >> 2);
  int t = threadIdx.x & 3;
  if (g >= NN) return;
  int node = perm[g];
  int s = off[node], e = off[node + 1];
  float accA = 0.0f;
  for (int p = s + t; p < e; p += 4) accA += ua[srcarr[p]];
  accA += __shfl_xor(accA, 1, 64); accA += __shfl_xor(accA, 2, 64);
  if (t == 0) {
    float sc;
    if (MODE == 0) { int c = e - s; sc = 1.0f / (float)(c > 0 ? c : 1); }
    else sc = dis[node];
    float rA = accA * sc + adda[node];
    if (biasa) rA += biasa[0];
    if (acta == 3) rA *= sc; else rA = act_apply(rA, acta);
    outa[node] = rA;
  }
}

// last chain-b hop (pre-scaled input) fused with final linear+relu
__global__ void k_g1_final(
    const float* __restrict__ ua, const float* __restrict__ adda,
    const float* __restrict__ biasa,
    const float* __restrict__ x1s, const float* __restrict__ x2s,
    const float* __restrict__ lw, const float* __restrict__ lb,
    const int* __restrict__ perm, const int* __restrict__ off,
    const int* __restrict__ srcarr, const float* __restrict__ dis,
    float* __restrict__ out) {
  int g = blockIdx.x * 64 + (threadIdx.x >> 2);
  int t = threadIdx.x & 3;
  if (g >= NN) return;
  int node = perm[g];
  int s = off[node], e = off[node + 1];
  float accA = 0.0f;
  for (int p = s + t; p < e; p += 4) accA += ua[srcarr[p]];
  accA += __shfl_xor(accA, 1, 64); accA += __shfl_xor(accA, 2, 64);
  if (t == 0) {
    float x3v = fmaxf(accA * dis[node] + adda[node] + biasa[0], 0.0f);
    float v = x1s[node] * lw[0] + x2s[node] * lw[1] + x3v * lw[2] + lb[0];
    out[node] = fmaxf(v, 0.0f);
  }
}

// ================= SAGE layer-1 fused GEMM (small K), fp16 out =================
template<int K1, int K2>
__global__ __launch_bounds__(256) void k_sage_mm(
    const float* __restrict__ A1, int as1, const float* __restrict__ A2, int as2,
    const float* __restrict__ W1, const float* __restrict__ W2,
    const float* __restrict__ bias, __half* __restrict__ out, int act) {
  constexpr int K = K1 + K2;
  constexpr int BM = 64;
  constexpr int BK = 32;
  __shared__ float Ash[BK][BM];
  __shared__ float Wsh[BK][128];
  int m0 = blockIdx.x * BM;
  int tid = threadIdx.x;
  int tx = tid & 15, ty = tid >> 4;
  int tm = ty * 4;
  int to = tx * 8;
  float acc[4][8] = {};
  for (int k0 = 0; k0 < K; k0 += BK) {
    {
      int mm = tid % BM, kb = tid / BM;
      #pragma unroll
      for (int it = 0; it < BK / 4; ++it) {
        int kk = kb + 4 * it;
        int gk = k0 + kk, gm = m0 + mm;
        float v = 0.0f;
        if (gm < NN && gk < K)
          v = (gk < K1) ? A1[(long)gm * as1 + gk] : A2[(long)gm * as2 + (gk - K1)];
        Ash[kk][mm] = v;
      }
    }
    {
      int oo = tid % 128, kb = tid / 128;
      #pragma unroll
      for (int it = 0; it < BK / 2; ++it) {
        int kk = kb + 2 * it;
        int gk = k0 + kk;
        float v = 0.0f;
        if (gk < K)
          v = (gk < K1) ? W1[oo * K1 + gk] : W2[oo * K2 + (gk - K1)];
        Wsh[kk][oo] = v;
      }
    }
    __syncthreads();
    #pragma unroll
    for (int kk = 0; kk < BK; ++kk) {
      float4 av = *reinterpret_cast<const float4*>(&Ash[kk][tm]);
      float4 wv0 = *reinterpret_cast<const float4*>(&Wsh[kk][to]);
      float4 wv1 = *reinterpret_cast<const float4*>(&Wsh[kk][to + 4]);
      float a[4] = {av.x, av.y, av.z, av.w};
      float w[8] = {wv0.x, wv0.y, wv0.z, wv0.w, wv1.x, wv1.y, wv1.z, wv1.w};
      #pragma unroll
      for (int i2 = 0; i2 < 4; ++i2)
        #pragma unroll
        for (int j = 0; j < 8; ++j)
          acc[i2][j] += a[i2] * w[j];
    }
    __syncthreads();
  }
  #pragma unroll
  for (int i2 = 0; i2 < 4; ++i2) {
    int gm = m0 + tm + i2;
    if (gm >= NN) continue;
    __half2* orow = (__half2*)(out + (long)gm * 128);
    #pragma unroll
    for (int j = 0; j < 4; ++j) {
      float lo = act_apply(acc[i2][2 * j] + bias[to + 2 * j], act);
      float hi = act_apply(acc[i2][2 * j + 1] + bias[to + 2 * j + 1], act);
      orow[to / 2 + j] = __floats2half2_rn(lo, hi);
    }
  }
}

// ================= SAGE layer-2 via MFMA fp16 + fused sigmoid/proj epilogue =================
__global__ __launch_bounds__(256) void k_mm2_mfma(
    const __half* __restrict__ A1, const __half* __restrict__ A2,
    const __half* __restrict__ W, const float* __restrict__ bias,
    const float* __restrict__ w3l, const float* __restrict__ w3r,
    float* __restrict__ pp, float* __restrict__ qq) {
  int tid = threadIdx.x;
  int wave = tid >> 6;
  int l = tid & 63;
  int lr = l & 15;
  int lk = l >> 4;
  int m0 = blockIdx.x * 128 + wave * 32;
  f4v acc[2][8] = {};
  #pragma unroll
  for (int ks = 0; ks < 8; ++ks) {
    const __half* Asrc = (ks < 4) ? A1 : A2;
    int kk = (ks & 3) * 32 + lk * 8;
    h8v afrag[2];
    #pragma unroll
    for (int rt = 0; rt < 2; ++rt) {
      int row = m0 + rt * 16 + lr;
      h8v z = {};
      afrag[rt] = (row < NN) ? *(const h8v*)&Asrc[(long)row * 128 + kk] : z;
    }
    #pragma unroll
    for (int c = 0; c < 8; ++c) {
      h8v bfrag = *(const h8v*)&W[(long)(c * 16 + lr) * 256 + ks * 32 + lk * 8];
      acc[0][c] = __builtin_amdgcn_mfma_f32_16x16x32_f16(afrag[0], bfrag, acc[0][c], 0, 0, 0);
      acc[1][c] = __builtin_amdgcn_mfma_f32_16x16x32_f16(afrag[1], bfrag, acc[1][c], 0, 0, 0);
    }
  }
  float wl[8], wr[8], bi[8];
  #pragma unroll
  for (int c = 0; c < 8; ++c) {
    wl[c] = w3l[c * 16 + lr];
    wr[c] = w3r[c * 16 + lr];
    bi[c] = bias[c * 16 + lr];
  }
  #pragma unroll
  for (int rt = 0; rt < 2; ++rt) {
    #pragma unroll
    for (int reg = 0; reg < 4; ++reg) {
      float s1 = 0.0f, s2 = 0.0f;
      #pragma unroll
      for (int c = 0; c < 8; ++c) {
        float v = acc[rt][c][reg] + bi[c];
        float sg = 1.0f / (1.0f + expf(-v));
        s1 += sg * wl[c];
        s2 += sg * wr[c];
      }
      #pragma unroll
      for (int d = 1; d < 16; d <<= 1) {
        s1 += __shfl_xor(s1, d, 64);
        s2 += __shfl_xor(s2, d, 64);
      }
      int row = m0 + rt * 16 + lk * 4 + reg;
      if (lr == 0 && row < NN) { pp[row] = s1; qq[row] = s2; }
    }
  }
}

// ================= TAG P-precompute =================
// f32 x input (KIN=11), NO=8: slices 0..NH-2 f32 adds; top slice fp16 pre-scaled by dis
template<int NH>
__global__ void k_tagP8(const float* __restrict__ A, const float* __restrict__ w,
                        const float* __restrict__ dis,
                        float* __restrict__ outAdds, __half* __restrict__ outTop) {
  int i = blockIdx.x * blockDim.x + threadIdx.x;
  if (i >= NN) return;
  float a[11];
  #pragma unroll
  for (int j = 0; j < 11; ++j) a[j] = A[(long)i * 11 + j];
  #pragma unroll
  for (int k = 0; k < NH; ++k) {
    float s[8];
    #pragma unroll
    for (int o = 0; o < 8; ++o) {
      float acc = 0.0f;
      #pragma unroll
      for (int j = 0; j < 11; ++j) acc += a[j] * w[o * (11 * NH) + k * 11 + j];
      s[o] = acc;
    }
    if (k < NH - 1) {
      float4* dst = (float4*)&outAdds[((long)k * NN + i) * 8];
      dst[0] = make_float4(s[0], s[1], s[2], s[3]);
      dst[1] = make_float4(s[4], s[5], s[6], s[7]);
    } else {
      float dn = dis[i];
      uint4 o4;
      __half2 q0 = __floats2half2_rn(s[0] * dn, s[1] * dn);
      __half2 q1 = __floats2half2_rn(s[2] * dn, s[3] * dn);
      __half2 q2 = __floats2half2_rn(s[4] * dn, s[5] * dn);
      __half2 q3 = __floats2half2_rn(s[6] * dn, s[7] * dn);
      o4.x = *(unsigned*)&q0; o4.y = *(unsigned*)&q1; o4.z = *(unsigned*)&q2; o4.w = *(unsigned*)&q3;
      ((uint4*)outTop)[i] = o4;
    }
  }
}

// fp16 [N][8] input, NO=1: out [NH][N]; top slice pre-scaled by dis
template<int NH>
__global__ void k_tagP1(const __half* __restrict__ A, const float* __restrict__ w,
                        const float* __restrict__ dis, float* __restrict__ out) {
  int i = blockIdx.x * blockDim.x + threadIdx.x;
  if (i >= NN) return;
  uint4 v = ((const uint4*)A)[i];
  float4 lo = h4f(make_uint2(v.x, v.y)), hi = h4f(make_uint2(v.z, v.w));
  float a[8] = {lo.x, lo.y, lo.z, lo.w, hi.x, hi.y, hi.z, hi.w};
  #pragma unroll
  for (int k = 0; k < NH; ++k) {
    float s = 0.0f;
    #pragma unroll
    for (int j = 0; j < 8; ++j) s += a[j] * w[k * 8 + j];
    if (k == NH - 1) s *= dis[i];
    out[(long)k * NN + i] = s;
  }
}

extern "C" void kernel_launch(void* const* d_in, const int* in_sizes, int n_in,
                              void* d_out, int out_size, void* d_ws, size_t ws_size,
                              hipStream_t stream) {
  const float* x    = (const float*)d_in[0];
  const int*   ei   = (const int*)d_in[1];
  const float* s1wl = (const float*)d_in[2];
  const float* s1wr = (const float*)d_in[3];
  const float* s1b  = (const float*)d_in[4];
  const float* s2wl = (const float*)d_in[5];
  const float* s2wr = (const float*)d_in[6];
  const float* s2b  = (const float*)d_in[7];
  const float* s3wl = (const float*)d_in[8];
  const float* s3wr = (const float*)d_in[9];
  const float* s3b  = (const float*)d_in[10];
  const float* t1aw = (const float*)d_in[11];
  const float* t1ab = (const float*)d_in[12];
  const float* t2aw = (const float*)d_in[13];
  const float* t2ab = (const float*)d_in[14];
  const float* t1bw = (const float*)d_in[15];
  const float* t1bb = (const float*)d_in[16];
  const float* t2bw = (const float*)d_in[17];
  const float* t2bb = (const float*)d_in[18];
  const float* lw   = (const float*)d_in[19];
  const float* lb   = (const float*)d_in[20];
  float* out = (float*)d_out;

  char* basep = (char*)d_ws;
  size_t off = 0;
  auto alloc = [&](size_t bytes) -> void* {
    void* ptr = basep + off;
    off = (off + bytes + 255) & ~(size_t)255;
    return ptr;
  };
  int*   cnt     = (int*)alloc((size_t)NN * 4);
  int*   csr_off = (int*)alloc((size_t)(NN + 1) * 4);
  float* dis     = (float*)alloc((size_t)NN * 4);
  int*   csr_src = (int*)alloc((size_t)EE * 4);
  uint2* pairs   = (uint2*)alloc((size_t)EE * 8);
  int*   perm    = (int*)alloc((size_t)NN * 4);
  int*   ghist   = (int*)alloc(256 * 4);
  int*   gcur    = (int*)alloc(256 * 4);
  int*   bexclB  = (int*)alloc(256 * 4);
  int*   hist    = (int*)alloc(NBIN * 4);
  int*   bincur  = (int*)alloc(NBIN * 4);
  float* x1s     = (float*)alloc((size_t)NN * 4);
  float* x2s     = (float*)alloc((size_t)NN * 4);
  float* pp      = (float*)alloc((size_t)NN * 4);
  float* qq      = (float*)alloc((size_t)NN * 4);
  float* uA1     = (float*)alloc((size_t)NN * 4);
  float* uA2     = (float*)alloc((size_t)NN * 4);
  float* uB1     = (float*)alloc((size_t)NN * 4);
  float* uB2     = (float*)alloc((size_t)NN * 4);
  __half* x12h   = (__half*)alloc((size_t)NN * 12 * 2);
  float* mean12  = (float*)alloc((size_t)NN * 12 * 4);
  __half* w2h    = (__half*)alloc((size_t)128 * 256 * 2);
  __half* x1a_h  = (__half*)alloc((size_t)NN * 128 * 2);   // region1 overlay after mm2
  __half* mean128_h = (__half*)alloc((size_t)NN * 128 * 2);
  float* region2 = (float*)alloc((size_t)NN * 72 * 4);

  // Region 1 overlay (x1a_h = 64N f32-equiv; reused after k_mm2_mfma):
  float* r1 = (float*)x1a_h;
  float*  Pa      = r1;                              // [3][N][8] = 24N (add slices 0..2)
  __half* PaTop_h = (__half*)(r1 + (size_t)NN * 24); // [N][8] fp16 prescaled = 4N
  __half* zaA     = (__half*)(r1 + (size_t)NN * 28);
  __half* zbA     = (__half*)(r1 + (size_t)NN * 32);
  __half* x2a     = (__half*)(r1 + (size_t)NN * 36);
  float*  P2      = r1 + (size_t)NN * 40;            // [4][N]; slice 3 prescaled
  // Region 2:
  float*  Pb      = region2;                              // [6][N][8] = 48N (adds 0..5)
  __half* PbTop_h = (__half*)(region2 + (size_t)NN * 48);
  __half* zaB     = (__half*)(region2 + (size_t)NN * 52);
  __half* zbB     = (__half*)(region2 + (size_t)NN * 56);
  __half* x3a     = (__half*)(region2 + (size_t)NN * 60);
  float*  P2b     = region2 + (size_t)NN * 64;            // [7][N]; slice 6 prescaled

  // ---- CSR build (bucketed) ----
  hipMemsetAsync(ghist, 0, 256 * 4, stream);
  k_bhist<<<512, 256, 0, stream>>>(ei, ghist);
  k_b196scan<<<1, 256, 0, stream>>>(ghist, gcur, bexclB, csr_off);
  k_split<<<(EE + 4095) / 4096, 256, 0, stream>>>(ei, gcur, pairs);
  k_bcount<<<NBK, 256, 0, stream>>>(pairs, bexclB, cnt, csr_off, dis);
  k_bfill<<<NBK, 256, 0, stream>>>(pairs, bexclB, csr_off, csr_src);

  // ---- degree sort ----
  hipMemsetAsync(hist, 0, NBIN * 4, stream);
  k_hist<<<(NN + 255) / 256, 256, 0, stream>>>(cnt, hist);
  k_binscan<<<1, 64, 0, stream>>>(hist, bincur);
  k_scatter<<<(NN + 255) / 256, 256, 0, stream>>>(cnt, bincur, perm);

  // ---- prep ----
  k_wcast<<<128, 256, 0, stream>>>(s2wl, s2wr, w2h);
  k_pad12h<<<(NN * 12 + 255) / 256, 256, 0, stream>>>(x, x12h);

  // ---- SAGE chain ----
  k_gmean12h<<<(NN + 63) / 64, 256, 0, stream>>>(x12h, perm, csr_off, csr_src, mean12);
  k_sage_mm<11, 11><<<(NN + 63) / 64, 256, 0, stream>>>(mean12, 12, x, 11, s1wl, s1wr, s1b, x1a_h, 1);
  k_gather128<<<(NN + 15) / 16, 256, 0, stream>>>(x1a_h, perm, csr_off, csr_src, mean128_h);
  k_mm2_mfma<<<(NN + 127) / 128, 256, 0, stream>>>(mean128_h, x1a_h, w2h, s2b, s3wl, s3wr, pp, qq);
  k_g1_single<0><<<(NN + 63) / 64, 256, 0, stream>>>(
      pp, qq, s3b, 2, perm, csr_off, csr_src, dis, x1s);

  // ---- TAG P precompute (after mm2 frees region1) ----
  k_tagP8<4><<<(NN + 255) / 256, 256, 0, stream>>>(x, t1aw, dis, Pa, PaTop_h);
  k_tagP8<7><<<(NN + 255) / 256, 256, 0, stream>>>(x, t1bw, dis, Pb, PbTop_h);

  const size_t S8 = (size_t)NN * 8;
  // ---- D=8 hops (chain a: 3 hops; chain b: 6 hops), fp16 prescaled streams ----
  k_g8h_dual<<<(NN + 127) / 128, 256, 0, stream>>>(
      PaTop_h, Pa + 2 * S8, nullptr, 3,
      PbTop_h, Pb + 5 * S8, nullptr, 3,
      perm, csr_off, csr_src, dis, zaA, zaB);
  k_g8h_dual<<<(NN + 127) / 128, 256, 0, stream>>>(
      zaA, Pa + 1 * S8, nullptr, 3,
      zaB, Pb + 4 * S8, nullptr, 3,
      perm, csr_off, csr_src, dis, zbA, zbB);
  k_g8h_dual<<<(NN + 127) / 128, 256, 0, stream>>>(
      zbA, Pa, t1ab, 1,
      zbB, Pb + 3 * S8, nullptr, 3,
      perm, csr_off, csr_src, dis, x2a, zaB);
  k_g8h_single<<<(NN + 127) / 128, 256, 0, stream>>>(
      zaB, Pb + 2 * S8, nullptr, 3, perm, csr_off, csr_src, dis, zbB);
  k_g8h_single<<<(NN + 127) / 128, 256, 0, stream>>>(
      zbB, Pb + 1 * S8, nullptr, 3, perm, csr_off, csr_src, dis, zaB);
  k_g8h_single<<<(NN + 127) / 128, 256, 0, stream>>>(
      zaB, Pb, t1bb, 1, perm, csr_off, csr_src, dis, x3a);

  // ---- second TAG linears ----
  k_tagP1<4><<<(NN + 255) / 256, 256, 0, stream>>>(x2a, t2aw, dis, P2);
  k_tagP1<7><<<(NN + 255) / 256, 256, 0, stream>>>(x3a, t2bw, dis, P2b);

  // ---- D=1 hops (prescaled f32 streams) ----
  k_g1_dual<1><<<(NN + 63) / 64, 256, 0, stream>>>(
      P2 + 3 * (size_t)NN, P2 + 2 * (size_t)NN, nullptr, 3,
      P2b + 6 * (size_t)NN, P2b + 5 * (size_t)NN, nullptr, 3,
      perm, csr_off, csr_src, dis, uA1, uB1);
  k_g1_dual<1><<<(NN + 63) / 64, 256, 0, stream>>>(
      uA1, P2 + 1 * (size_t)NN, nullptr, 3,
      uB1, P2b + 4 * (size_t)NN, nullptr, 3,
      perm, csr_off, csr_src, dis, uA2, uB2);
  k_g1_dual<1><<<(NN + 63) / 64, 256, 0, stream>>>(
      uA2, P2, t2ab, 2,
      uB2, P2b + 3 * (size_t)NN, nullptr, 3,
      perm, csr_off, csr_src, dis, x2s, uB1);
  k_g1_single<1><<<(NN + 63) / 64, 256, 0, stream>>>(
      uB1, P2b + 2 * (size_t)NN, nullptr, 3, perm, csr_off, csr_src, dis, uB2);
  k_g1_single<1><<<(NN + 63) / 64, 256, 0, stream>>>(
      uB2, P2b + 1 * (size_t)NN, nullptr, 3, perm, csr_off, csr_src, dis, uB1);
  k_g1_final<<<(NN + 63) / 64, 256, 0, stream>>>(
      uB1, P2b, t2bb, x1s, x2s, lw, lb, perm, csr_off, csr_src, dis, out);
}

// Round 6
// 542.765 us; speedup vs baseline: 2.9704x; 1.1271x over previous
//
#include <hip/hip_runtime.h>
#include <hip/hip_bf16.h>
#include <hip/hip_fp16.h>

#define NN 100000
#define EE 1600000
#define NBIN 64
#define BSH 9
#define BSZ 512
#define NBK 196   // ceil(NN/512)

typedef _Float16 h8v __attribute__((ext_vector_type(8)));
typedef float f4v __attribute__((ext_vector_type(4)));

__device__ __forceinline__ float act_apply(float v, int act) {
  if (act == 1) return 1.0f / (1.0f + expf(-v));
  if (act == 2) return fmaxf(v, 0.0f);
  return v;
}
__device__ __forceinline__ float4 f4add(float4 a, float4 b) {
  a.x += b.x; a.y += b.y; a.z += b.z; a.w += b.w; return a;
}
__device__ __forceinline__ float4 f4scale(float4 a, float s) {
  a.x *= s; a.y *= s; a.z *= s; a.w *= s; return a;
}
__device__ __forceinline__ float4 h4f(uint2 v) {
  __half2 a = *reinterpret_cast<__half2*>(&v.x);
  __half2 b = *reinterpret_cast<__half2*>(&v.y);
  float2 fa = __half22float2(a), fb = __half22float2(b);
  return make_float4(fa.x, fa.y, fb.x, fb.y);
}
__device__ __forceinline__ void h8acc(uint4 v, float* a) {
  float4 lo = h4f(make_uint2(v.x, v.y));
  float4 hi = h4f(make_uint2(v.z, v.w));
  a[0] += lo.x; a[1] += lo.y; a[2] += lo.z; a[3] += lo.w;
  a[4] += hi.x; a[5] += hi.y; a[6] += hi.z; a[7] += hi.w;
}
__device__ __forceinline__ uint2 pack4h(float4 r) {
  __half2 q0 = __floats2half2_rn(r.x, r.y), q1 = __floats2half2_rn(r.z, r.w);
  uint2 o; o.x = *(unsigned*)&q0; o.y = *(unsigned*)&q1; return o;
}

// ================= CSR build (bucketed, XCD-local writes) =================
__global__ __launch_bounds__(256) void k_bhist(const int* __restrict__ ei, int* __restrict__ ghist) {
  __shared__ int lh[NBK];
  for (int j = threadIdx.x; j < NBK; j += 256) lh[j] = 0;
  __syncthreads();
  for (int i = blockIdx.x * 256 + threadIdx.x; i < EE; i += gridDim.x * 256)
    atomicAdd(&lh[ei[EE + i] >> BSH], 1);
  __syncthreads();
  for (int j = threadIdx.x; j < NBK; j += 256) {
    int v = lh[j];
    if (v) atomicAdd(&ghist[j], v);
  }
}

__global__ void k_b196scan(const int* __restrict__ ghist, int* __restrict__ gcur,
                           int* __restrict__ bexclB, int* __restrict__ csr_off) {
  __shared__ int sh[256];
  int tid = threadIdx.x;
  int v = (tid < NBK) ? ghist[tid] : 0;
  sh[tid] = v;
  __syncthreads();
  for (int d = 1; d < 256; d <<= 1) {
    int t = (tid >= d) ? sh[tid - d] : 0;
    __syncthreads();
    sh[tid] += t;
    __syncthreads();
  }
  int excl = sh[tid] - v;
  if (tid < NBK) { gcur[tid] = excl; bexclB[tid] = excl; }
  if (tid == 0) { bexclB[NBK] = EE; csr_off[NN] = EE; }
}

__global__ __launch_bounds__(256) void k_split(const int* __restrict__ ei,
                                               int* __restrict__ gcur,
                                               uint2* __restrict__ pairs) {
  __shared__ int cntL[256];
  __shared__ int segO[256];
  __shared__ int curL[256];
  __shared__ int baseL[256];
  __shared__ uint2 stag[4096];
  int tid = threadIdx.x;
  int tile0 = blockIdx.x * 4096;
  int tcnt = min(4096, EE - tile0);
  cntL[tid] = 0; curL[tid] = 0;
  __syncthreads();
  for (int i = tid; i < tcnt; i += 256)
    atomicAdd(&cntL[ei[EE + tile0 + i] >> BSH], 1);
  __syncthreads();
  int v = cntL[tid];
  segO[tid] = v;
  __syncthreads();
  for (int d = 1; d < 256; d <<= 1) {
    int t = (tid >= d) ? segO[tid - d] : 0;
    __syncthreads();
    segO[tid] += t;
    __syncthreads();
  }
  int excl = segO[tid] - v;
  __syncthreads();
  segO[tid] = excl;
  __syncthreads();
  for (int i = tid; i < tcnt; i += 256) {
    int s = ei[tile0 + i], dd = ei[EE + tile0 + i];
    int b = dd >> BSH;
    int slot = segO[b] + atomicAdd(&curL[b], 1);
    stag[slot] = make_uint2((unsigned)s, (unsigned)dd);
  }
  baseL[tid] = v ? atomicAdd(&gcur[tid], v) : 0;
  __syncthreads();
  for (int i = tid; i < tcnt; i += 256) {
    uint2 pr = stag[i];
    int b = (int)(pr.y >> BSH);
    pairs[baseL[b] + (i - segO[b])] = pr;
  }
}

__global__ __launch_bounds__(256) void k_bcount(const uint2* __restrict__ pairs,
                                                const int* __restrict__ bexclB,
                                                int* __restrict__ cnt, int* __restrict__ csr_off,
                                                float* __restrict__ dis) {
  __shared__ int c[BSZ];
  __shared__ int ps[256];
  int tid = threadIdx.x;
  int b = blockIdx.x;
  int lo = b << BSH;
  for (int j = tid; j < BSZ; j += 256) c[j] = 0;
  __syncthreads();
  int s0e = bexclB[b], s1e = bexclB[b + 1];
  for (int i = s0e + tid; i < s1e; i += 256)
    atomicAdd(&c[pairs[i].y - lo], 1);
  __syncthreads();
  int a0 = c[2 * tid], a1 = c[2 * tid + 1];
  int pv = a0 + a1;
  ps[tid] = pv;
  __syncthreads();
  for (int d = 1; d < 256; d <<= 1) {
    int t = (tid >= d) ? ps[tid - d] : 0;
    __syncthreads();
    ps[tid] += t;
    __syncthreads();
  }
  int pex = ps[tid] - pv;
  int base = s0e + pex;
  int n0 = lo + 2 * tid, n1 = n0 + 1;
  if (n0 < NN) {
    csr_off[n0] = base; cnt[n0] = a0;
    dis[n0] = (a0 > 0) ? rsqrtf((float)a0) : 0.0f;
  }
  if (n1 < NN) {
    csr_off[n1] = base + a0; cnt[n1] = a1;
    dis[n1] = (a1 > 0) ? rsqrtf((float)a1) : 0.0f;
  }
}

__global__ __launch_bounds__(256) void k_bfill(const uint2* __restrict__ pairs,
                                               const int* __restrict__ bexclB,
                                               const int* __restrict__ csr_off,
                                               int* __restrict__ csr_src) {
  __shared__ int cur[BSZ];
  int tid = threadIdx.x;
  int b = blockIdx.x;
  int lo = b << BSH;
  for (int j = tid; j < BSZ; j += 256) {
    int n = lo + j;
    cur[j] = (n < NN) ? csr_off[n] : 0;
  }
  __syncthreads();
  int s0e = bexclB[b], s1e = bexclB[b + 1];
  for (int i = s0e + tid; i < s1e; i += 256) {
    uint2 pr = pairs[i];
    int p = atomicAdd(&cur[pr.y - lo], 1);
    csr_src[p] = (int)pr.x;
  }
}

// ================= degree sort (perm) =================
__global__ __launch_bounds__(256) void k_hist(const int* __restrict__ cnt, int* __restrict__ hist) {
  __shared__ int lh[NBIN];
  if (threadIdx.x < NBIN) lh[threadIdx.x] = 0;
  __syncthreads();
  int i = blockIdx.x * 256 + threadIdx.x;
  if (i < NN) atomicAdd(&lh[min(cnt[i], NBIN - 1)], 1);
  __syncthreads();
  if (threadIdx.x < NBIN) {
    int v = lh[threadIdx.x];
    if (v) atomicAdd(&hist[threadIdx.x], v);
  }
}
__global__ void k_binscan(const int* __restrict__ hist, int* __restrict__ bincur) {
  int tid = threadIdx.x;
  int v = hist[tid];
  int incl = v;
  for (int d = 1; d < 64; d <<= 1) {
    int t = __shfl_up(incl, d, 64);
    if (tid >= d) incl += t;
  }
  bincur[tid] = incl - v;
}
__global__ __launch_bounds__(256) void k_scatter(const int* __restrict__ cnt,
                                                 int* __restrict__ bincur,
                                                 int* __restrict__ perm) {
  __shared__ int lh[NBIN];
  __shared__ int lbase[NBIN];
  if (threadIdx.x < NBIN) lh[threadIdx.x] = 0;
  __syncthreads();
  int i = blockIdx.x * 256 + threadIdx.x;
  int b = 0, r = 0;
  bool valid = i < NN;
  if (valid) {
    b = min(cnt[i], NBIN - 1);
    r = atomicAdd(&lh[b], 1);
  }
  __syncthreads();
  if (threadIdx.x < NBIN) {
    int v = lh[threadIdx.x];
    lbase[threadIdx.x] = v ? atomicAdd(&bincur[threadIdx.x], v) : 0;
  }
  __syncthreads();
  if (valid) perm[lbase[b] + r] = i;
}

// ================= feature prep =================
__global__ void k_pad12h(const float* __restrict__ x, __half* __restrict__ x12h) {
  int i = blockIdx.x * blockDim.x + threadIdx.x;
  if (i >= NN * 12) return;
  int n = i / 12, j = i - n * 12;
  x12h[i] = __float2half((j < 11) ? x[n * 11 + j] : 0.0f);
}

// A32 [N][32] fp16: slots 4,5,6 = x fp16 (cols 16..26, col27=0); slots 3,7 = 0.
__global__ void k_prep_a32(const float* __restrict__ x, __half* __restrict__ A32) {
  int i = blockIdx.x * blockDim.x + threadIdx.x;
  if (i >= NN) return;
  float a[11];
  #pragma unroll
  for (int j = 0; j < 11; ++j) a[j] = x[(long)i * 11 + j];
  uint2* row = (uint2*)(A32 + (long)i * 32);
  row[3] = make_uint2(0u, 0u);
  row[4] = pack4h(make_float4(a[0], a[1], a[2], a[3]));
  row[5] = pack4h(make_float4(a[4], a[5], a[6], a[7]));
  row[6] = pack4h(make_float4(a[8], a[9], a[10], 0.0f));
  row[7] = make_uint2(0u, 0u);
}

// W32 [128][32] fp16: cols 0..10 = s1wl, 16..26 = s1wr, rest 0
__global__ void k_wcast1(const float* __restrict__ wl, const float* __restrict__ wr,
                         __half* __restrict__ w1h) {
  int i = blockIdx.x * 256 + threadIdx.x;
  if (i >= 128 * 32) return;
  int o = i >> 5, k = i & 31;
  float v = 0.0f;
  if (k < 11) v = wl[o * 11 + k];
  else if (k >= 16 && k < 27) v = wr[o * 11 + (k - 16)];
  w1h[i] = __float2half(v);
}

__global__ void k_wcast(const float* __restrict__ wl, const float* __restrict__ wr,
                        __half* __restrict__ w2h) {
  int i = blockIdx.x * 256 + threadIdx.x;
  if (i >= 128 * 256) return;
  int o = i >> 8, k = i & 255;
  float v = (k < 128) ? wl[o * 128 + k] : wr[o * 128 + (k - 128)];
  w2h[i] = __float2half(v);
}

// ================= gathers =================
// SAGE mean D=12 fp16 in, writes A32 cols 0..11 (uint2 slots 0..2)
__global__ void k_gmean12h(const __half* __restrict__ x12h, const int* __restrict__ perm,
                           const int* __restrict__ off, const int* __restrict__ srcarr,
                           __half* __restrict__ A32) {
  int g = blockIdx.x * 64 + (threadIdx.x >> 2);
  int t = threadIdx.x & 3;
  if (g >= NN || t >= 3) return;
  int node = perm[g];
  int s = off[node], e = off[node + 1];
  const uint2* h2 = (const uint2*)x12h;   // 4 halves each; node stride 3
  float4 acc = {0, 0, 0, 0};
  int p = s;
  for (; p + 4 <= e; p += 4) {
    int s0 = srcarr[p], s1 = srcarr[p + 1], s2 = srcarr[p + 2], s3 = srcarr[p + 3];
    acc = f4add(acc, f4add(f4add(h4f(h2[(long)s0 * 3 + t]), h4f(h2[(long)s1 * 3 + t])),
                           f4add(h4f(h2[(long)s2 * 3 + t]), h4f(h2[(long)s3 * 3 + t]))));
  }
  for (; p < e; ++p) acc = f4add(acc, h4f(h2[(long)srcarr[p] * 3 + t]));
  int c = e - s;
  float inv = 1.0f / (float)(c > 0 ? c : 1);
  ((uint2*)A32)[(long)node * 8 + t] = pack4h(f4scale(acc, inv));
}

// SAGE mean, D=128 fp16 in/out, G=16 lanes (uint4 = 8 halves)
__global__ void k_gather128(const __half* __restrict__ h, const int* __restrict__ perm,
                            const int* __restrict__ off, const int* __restrict__ srcarr,
                            __half* __restrict__ outh) {
  int g = blockIdx.x * 16 + (threadIdx.x >> 4);
  int t = threadIdx.x & 15;
  if (g >= NN) return;
  int node = perm[g];
  int s = off[node], e = off[node + 1];
  const uint4* h4 = (const uint4*)h;
  float acc[8] = {};
  int p = s;
  for (; p + 4 <= e; p += 4) {
    int s0 = srcarr[p], s1 = srcarr[p + 1], s2 = srcarr[p + 2], s3 = srcarr[p + 3];
    uint4 r0 = h4[(long)s0 * 16 + t], r1 = h4[(long)s1 * 16 + t];
    uint4 r2 = h4[(long)s2 * 16 + t], r3 = h4[(long)s3 * 16 + t];
    h8acc(r0, acc); h8acc(r1, acc); h8acc(r2, acc); h8acc(r3, acc);
  }
  for (; p < e; ++p) h8acc(h4[(long)srcarr[p] * 16 + t], acc);
  int c = e - s;
  float inv = 1.0f / (float)(c > 0 ? c : 1);
  uint4 o;
  __half2 p0 = __floats2half2_rn(acc[0] * inv, acc[1] * inv);
  __half2 p1 = __floats2half2_rn(acc[2] * inv, acc[3] * inv);
  __half2 p2 = __floats2half2_rn(acc[4] * inv, acc[5] * inv);
  __half2 p3 = __floats2half2_rn(acc[6] * inv, acc[7] * inv);
  o.x = *(unsigned*)&p0; o.y = *(unsigned*)&p1; o.z = *(unsigned*)&p2; o.w = *(unsigned*)&p3;
  ((uint4*)outh)[(long)node * 16 + t] = o;
}

// TAG D=8, fp16 pre-scaled streams. acts: 1=sig, 2=relu, 3=prescale-store
__global__ void k_g8h_dual(
    const __half* __restrict__ ha, const float* __restrict__ adda,
    const float* __restrict__ biasa, int acta,
    const __half* __restrict__ hb, const float* __restrict__ addb,
    const float* __restrict__ biasb, int actb,
    const int* __restrict__ perm, const int* __restrict__ off,
    const int* __restrict__ srcarr, const float* __restrict__ dis,
    __half* __restrict__ outa, __half* __restrict__ outb) {
  int g = blockIdx.x * 128 + (threadIdx.x >> 1);
  int t = threadIdx.x & 1;
  if (g >= NN) return;
  int node = perm[g];
  int s = off[node], e = off[node + 1];
  const uint2* ha2 = (const uint2*)ha;
  const uint2* hb2 = (const uint2*)hb;
  float4 accA = {0, 0, 0, 0}, accB = {0, 0, 0, 0};
  int p = s;
  for (; p + 4 <= e; p += 4) {
    int s0 = srcarr[p], s1 = srcarr[p + 1], s2 = srcarr[p + 2], s3 = srcarr[p + 3];
    accA = f4add(accA, f4add(f4add(h4f(ha2[(long)s0 * 2 + t]), h4f(ha2[(long)s1 * 2 + t])),
                             f4add(h4f(ha2[(long)s2 * 2 + t]), h4f(ha2[(long)s3 * 2 + t]))));
    accB = f4add(accB, f4add(f4add(h4f(hb2[(long)s0 * 2 + t]), h4f(hb2[(long)s1 * 2 + t])),
                             f4add(h4f(hb2[(long)s2 * 2 + t]), h4f(hb2[(long)s3 * 2 + t]))));
  }
  for (; p < e; ++p) {
    int s0 = srcarr[p];
    accA = f4add(accA, h4f(ha2[(long)s0 * 2 + t]));
    accB = f4add(accB, h4f(hb2[(long)s0 * 2 + t]));
  }
  float dn = dis[node];
  float4 rA = f4scale(accA, dn);
  rA = f4add(rA, ((const float4*)adda)[(long)node * 2 + t]);
  if (biasa) rA = f4add(rA, ((const float4*)biasa)[t]);
  if (acta == 1) { rA.x = act_apply(rA.x, 1); rA.y = act_apply(rA.y, 1); rA.z = act_apply(rA.z, 1); rA.w = act_apply(rA.w, 1); }
  else if (acta == 2) { rA.x = fmaxf(rA.x, 0.f); rA.y = fmaxf(rA.y, 0.f); rA.z = fmaxf(rA.z, 0.f); rA.w = fmaxf(rA.w, 0.f); }
  else if (acta == 3) rA = f4scale(rA, dn);
  ((uint2*)outa)[(long)node * 2 + t] = pack4h(rA);
  float4 rB = f4scale(accB, dn);
  rB = f4add(rB, ((const float4*)addb)[(long)node * 2 + t]);
  if (biasb) rB = f4add(rB, ((const float4*)biasb)[t]);
  if (actb == 1) { rB.x = act_apply(rB.x, 1); rB.y = act_apply(rB.y, 1); rB.z = act_apply(rB.z, 1); rB.w = act_apply(rB.w, 1); }
  else if (actb == 2) { rB.x = fmaxf(rB.x, 0.f); rB.y = fmaxf(rB.y, 0.f); rB.z = fmaxf(rB.z, 0.f); rB.w = fmaxf(rB.w, 0.f); }
  else if (actb == 3) rB = f4scale(rB, dn);
  ((uint2*)outb)[(long)node * 2 + t] = pack4h(rB);
}

__global__ void k_g8h_single(
    const __half* __restrict__ ha, const float* __restrict__ adda,
    const float* __restrict__ biasa, int acta,
    const int* __restrict__ perm, const int* __restrict__ off,
    const int* __restrict__ srcarr, const float* __restrict__ dis,
    __half* __restrict__ outa) {
  int g = blockIdx.x * 128 + (threadIdx.x >> 1);
  int t = threadIdx.x & 1;
  if (g >= NN) return;
  int node = perm[g];
  int s = off[node], e = off[node + 1];
  const uint2* ha2 = (const uint2*)ha;
  float4 accA = {0, 0, 0, 0};
  int p = s;
  for (; p + 4 <= e; p += 4) {
    int s0 = srcarr[p], s1 = srcarr[p + 1], s2 = srcarr[p + 2], s3 = srcarr[p + 3];
    accA = f4add(accA, f4add(f4add(h4f(ha2[(long)s0 * 2 + t]), h4f(ha2[(long)s1 * 2 + t])),
                             f4add(h4f(ha2[(long)s2 * 2 + t]), h4f(ha2[(long)s3 * 2 + t]))));
  }
  for (; p < e; ++p) accA = f4add(accA, h4f(ha2[(long)srcarr[p] * 2 + t]));
  float dn = dis[node];
  float4 rA = f4scale(accA, dn);
  rA = f4add(rA, ((const float4*)adda)[(long)node * 2 + t]);
  if (biasa) rA = f4add(rA, ((const float4*)biasa)[t]);
  if (acta == 1) { rA.x = act_apply(rA.x, 1); rA.y = act_apply(rA.y, 1); rA.z = act_apply(rA.z, 1); rA.w = act_apply(rA.w, 1); }
  else if (acta == 3) rA = f4scale(rA, dn);
  ((uint2*)outa)[(long)node * 2 + t] = pack4h(rA);
}

// D=1 gathers, pre-scaled f32 streams. MODE 0 = mean (SAGE), 1 = tag-norm.
template<int MODE>
__global__ void k_g1_dual(
    const float* __restrict__ ua, const float* __restrict__ adda,
    const float* __restrict__ biasa, int acta,
    const float* __restrict__ ub, const float* __restrict__ addb,
    const float* __restrict__ biasb, int actb,
    const int* __restrict__ perm, const int* __restrict__ off,
    const int* __restrict__ srcarr, const float* __restrict__ dis,
    float* __restrict__ outa, float* __restrict__ outb) {
  int g = blockIdx.x * 64 + (threadIdx.x >> 2);
  int t = threadIdx.x & 3;
  if (g >= NN) return;
  int node = perm[g];
  int s = off[node], e = off[node + 1];
  float accA = 0.0f, accB = 0.0f;
  for (int p = s + t; p < e; p += 4) {
    int s0 = srcarr[p];
    accA += ua[s0];
    accB += ub[s0];
  }
  accA += __shfl_xor(accA, 1, 64); accA += __shfl_xor(accA, 2, 64);
  accB += __shfl_xor(accB, 1, 64); accB += __shfl_xor(accB, 2, 64);
  if (t == 0) {
    float sc;
    if (MODE == 0) { int c = e - s; sc = 1.0f / (float)(c > 0 ? c : 1); }
    else sc = dis[node];
    float rA = accA * sc + adda[node];
    if (biasa) rA += biasa[0];
    if (acta == 3) rA *= sc; else rA = act_apply(rA, acta);
    outa[node] = rA;
    float rB = accB * sc + addb[node];
    if (biasb) rB += biasb[0];
    if (actb == 3) rB *= sc; else rB = act_apply(rB, actb);
    outb[node] = rB;
  }
}

template<int MODE>
__global__ void k_g1_single(
    const float* __restrict__ ua, const float* __restrict__ adda,
    const float* __restrict__ biasa, int acta,
    const int* __restrict__ perm, const int* __restrict__ off,
    const int* __restrict__ srcarr, const float* __restrict__ dis,
    float* __restrict__ outa) {
  int g = blockIdx.x * 64 + (threadIdx.x >> 2);
  int t = threadIdx.x & 3;
  if (g >= NN) return;
  int node = perm[g];
  int s = off[node], e = off[node + 1];
  float accA = 0.0f;
  for (int p = s + t; p < e; p += 4) accA += ua[srcarr[p]];
  accA += __shfl_xor(accA, 1, 64); accA += __shfl_xor(accA, 2, 64);
  if (t == 0) {
    float sc;
    if (MODE == 0) { int c = e - s; sc = 1.0f / (float)(c > 0 ? c : 1); }
    else sc = dis[node];
    float rA = accA * sc + adda[node];
    if (biasa) rA += biasa[0];
    if (acta == 3) rA *= sc; else rA = act_apply(rA, acta);
    outa[node] = rA;
  }
}

__global__ void k_g1_final(
    const float* __restrict__ ua, const float* __restrict__ adda,
    const float* __restrict__ biasa,
    const float* __restrict__ x1s, const float* __restrict__ x2s,
    const float* __restrict__ lw, const float* __restrict__ lb,
    const int* __restrict__ perm, const int* __restrict__ off,
    const int* __restrict__ srcarr, const float* __restrict__ dis,
    float* __restrict__ out) {
  int g = blockIdx.x * 64 + (threadIdx.x >> 2);
  int t = threadIdx.x & 3;
  if (g >= NN) return;
  int node = perm[g];
  int s = off[node], e = off[node + 1];
  float accA = 0.0f;
  for (int p = s + t; p < e; p += 4) accA += ua[srcarr[p]];
  accA += __shfl_xor(accA, 1, 64); accA += __shfl_xor(accA, 2, 64);
  if (t == 0) {
    float x3v = fmaxf(accA * dis[node] + adda[node] + biasa[0], 0.0f);
    float v = x1s[node] * lw[0] + x2s[node] * lw[1] + x3v * lw[2] + lb[0];
    out[node] = fmaxf(v, 0.0f);
  }
}

// ================= SAGE layer-1 via MFMA (K=32 padded), sigmoid, fp16 out =================
// A32 [N][32] fp16, W32 [128][32] fp16. One MFMA k-step per tile.
__global__ __launch_bounds__(256) void k_mm1_mfma(
    const __half* __restrict__ A32, const __half* __restrict__ W32,
    const float* __restrict__ bias, __half* __restrict__ out) {
  __shared__ __half lt[4][32][136];   // 136-half row stride: 272B = 17x16B (aligned, bank-spread)
  int tid = threadIdx.x;
  int wave = tid >> 6, l = tid & 63;
  int lr = l & 15, lk = l >> 4;
  int m0 = blockIdx.x * 128 + wave * 32;
  f4v acc[2][8] = {};
  h8v afrag[2];
  #pragma unroll
  for (int rt = 0; rt < 2; ++rt) {
    int row = m0 + rt * 16 + lr;
    h8v z = {};
    afrag[rt] = (row < NN) ? *(const h8v*)&A32[(long)row * 32 + lk * 8] : z;
  }
  #pragma unroll
  for (int c = 0; c < 8; ++c) {
    h8v bfrag = *(const h8v*)&W32[(c * 16 + lr) * 32 + lk * 8];
    acc[0][c] = __builtin_amdgcn_mfma_f32_16x16x32_f16(afrag[0], bfrag, acc[0][c], 0, 0, 0);
    acc[1][c] = __builtin_amdgcn_mfma_f32_16x16x32_f16(afrag[1], bfrag, acc[1][c], 0, 0, 0);
  }
  float bi[8];
  #pragma unroll
  for (int c = 0; c < 8; ++c) bi[c] = bias[c * 16 + lr];
  #pragma unroll
  for (int rt = 0; rt < 2; ++rt)
    #pragma unroll
    for (int c = 0; c < 8; ++c)
      #pragma unroll
      for (int reg = 0; reg < 4; ++reg) {
        float v = acc[rt][c][reg] + bi[c];
        lt[wave][rt * 16 + lk * 4 + reg][c * 16 + lr] = __float2half(1.0f / (1.0f + expf(-v)));
      }
  __syncthreads();
  #pragma unroll
  for (int it = 0; it < 8; ++it) {
    int idx = it * 64 + l;          // 0..511
    int row = idx >> 4, c16 = idx & 15;
    int grow = m0 + row;
    if (grow < NN) {
      uint4 v = *(const uint4*)&lt[wave][row][c16 * 8];
      ((uint4*)out)[(long)grow * 16 + c16] = v;
    }
  }
}

// ================= SAGE layer-2 via MFMA fp16 + fused sigmoid/proj epilogue =================
__global__ __launch_bounds__(256) void k_mm2_mfma(
    const __half* __restrict__ A1, const __half* __restrict__ A2,
    const __half* __restrict__ W, const float* __restrict__ bias,
    const float* __restrict__ w3l, const float* __restrict__ w3r,
    float* __restrict__ pp, float* __restrict__ qq) {
  int tid = threadIdx.x;
  int wave = tid >> 6;
  int l = tid & 63;
  int lr = l & 15;
  int lk = l >> 4;
  int m0 = blockIdx.x * 128 + wave * 32;
  f4v acc[2][8] = {};
  #pragma unroll
  for (int ks = 0; ks < 8; ++ks) {
    const __half* Asrc = (ks < 4) ? A1 : A2;
    int kk = (ks & 3) * 32 + lk * 8;
    h8v afrag[2];
    #pragma unroll
    for (int rt = 0; rt < 2; ++rt) {
      int row = m0 + rt * 16 + lr;
      h8v z = {};
      afrag[rt] = (row < NN) ? *(const h8v*)&Asrc[(long)row * 128 + kk] : z;
    }
    #pragma unroll
    for (int c = 0; c < 8; ++c) {
      h8v bfrag = *(const h8v*)&W[(long)(c * 16 + lr) * 256 + ks * 32 + lk * 8];
      acc[0][c] = __builtin_amdgcn_mfma_f32_16x16x32_f16(afrag[0], bfrag, acc[0][c], 0, 0, 0);
      acc[1][c] = __builtin_amdgcn_mfma_f32_16x16x32_f16(afrag[1], bfrag, acc[1][c], 0, 0, 0);
    }
  }
  float wl[8], wr[8], bi[8];
  #pragma unroll
  for (int c = 0; c < 8; ++c) {
    wl[c] = w3l[c * 16 + lr];
    wr[c] = w3r[c * 16 + lr];
    bi[c] = bias[c * 16 + lr];
  }
  #pragma unroll
  for (int rt = 0; rt < 2; ++rt) {
    #pragma unroll
    for (int reg = 0; reg < 4; ++reg) {
      float s1 = 0.0f, s2 = 0.0f;
      #pragma unroll
      for (int c = 0; c < 8; ++c) {
        float v = acc[rt][c][reg] + bi[c];
        float sg = 1.0f / (1.0f + expf(-v));
        s1 += sg * wl[c];
        s2 += sg * wr[c];
      }
      #pragma unroll
      for (int d = 1; d < 16; d <<= 1) {
        s1 += __shfl_xor(s1, d, 64);
        s2 += __shfl_xor(s2, d, 64);
      }
      int row = m0 + rt * 16 + lk * 4 + reg;
      if (lr == 0 && row < NN) { pp[row] = s1; qq[row] = s2; }
    }
  }
}

// ================= TAG P-precompute =================
template<int NH>
__global__ void k_tagP8(const float* __restrict__ A, const float* __restrict__ w,
                        const float* __restrict__ dis,
                        float* __restrict__ outAdds, __half* __restrict__ outTop) {
  int i = blockIdx.x * blockDim.x + threadIdx.x;
  if (i >= NN) return;
  float a[11];
  #pragma unroll
  for (int j = 0; j < 11; ++j) a[j] = A[(long)i * 11 + j];
  #pragma unroll
  for (int k = 0; k < NH; ++k) {
    float s[8];
    #pragma unroll
    for (int o = 0; o < 8; ++o) {
      float acc = 0.0f;
      #pragma unroll
      for (int j = 0; j < 11; ++j) acc += a[j] * w[o * (11 * NH) + k * 11 + j];
      s[o] = acc;
    }
    if (k < NH - 1) {
      float4* dst = (float4*)&outAdds[((long)k * NN + i) * 8];
      dst[0] = make_float4(s[0], s[1], s[2], s[3]);
      dst[1] = make_float4(s[4], s[5], s[6], s[7]);
    } else {
      float dn = dis[i];
      uint4 o4;
      __half2 q0 = __floats2half2_rn(s[0] * dn, s[1] * dn);
      __half2 q1 = __floats2half2_rn(s[2] * dn, s[3] * dn);
      __half2 q2 = __floats2half2_rn(s[4] * dn, s[5] * dn);
      __half2 q3 = __floats2half2_rn(s[6] * dn, s[7] * dn);
      o4.x = *(unsigned*)&q0; o4.y = *(unsigned*)&q1; o4.z = *(unsigned*)&q2; o4.w = *(unsigned*)&q3;
      ((uint4*)outTop)[i] = o4;
    }
  }
}

template<int NH>
__global__ void k_tagP1(const __half* __restrict__ A, const float* __restrict__ w,
                        const float* __restrict__ dis, float* __restrict__ out) {
  int i = blockIdx.x * blockDim.x + threadIdx.x;
  if (i >= NN) return;
  uint4 v = ((const uint4*)A)[i];
  float4 lo = h4f(make_uint2(v.x, v.y)), hi = h4f(make_uint2(v.z, v.w));
  float a[8] = {lo.x, lo.y, lo.z, lo.w, hi.x, hi.y, hi.z, hi.w};
  #pragma unroll
  for (int k = 0; k < NH; ++k) {
    float s = 0.0f;
    #pragma unroll
    for (int j = 0; j < 8; ++j) s += a[j] * w[k * 8 + j];
    if (k == NH - 1) s *= dis[i];
    out[(long)k * NN + i] = s;
  }
}

extern "C" void kernel_launch(void* const* d_in, const int* in_sizes, int n_in,
                              void* d_out, int out_size, void* d_ws, size_t ws_size,
                              hipStream_t stream) {
  const float* x    = (const float*)d_in[0];
  const int*   ei   = (const int*)d_in[1];
  const float* s1wl = (const float*)d_in[2];
  const float* s1wr = (const float*)d_in[3];
  const float* s1b  = (const float*)d_in[4];
  const float* s2wl = (const float*)d_in[5];
  const float* s2wr = (const float*)d_in[6];
  const float* s2b  = (const float*)d_in[7];
  const float* s3wl = (const float*)d_in[8];
  const float* s3wr = (const float*)d_in[9];
  const float* s3b  = (const float*)d_in[10];
  const float* t1aw = (const float*)d_in[11];
  const float* t1ab = (const float*)d_in[12];
  const float* t2aw = (const float*)d_in[13];
  const float* t2ab = (const float*)d_in[14];
  const float* t1bw = (const float*)d_in[15];
  const float* t1bb = (const float*)d_in[16];
  const float* t2bw = (const float*)d_in[17];
  const float* t2bb = (const float*)d_in[18];
  const float* lw   = (const float*)d_in[19];
  const float* lb   = (const float*)d_in[20];
  float* out = (float*)d_out;

  char* basep = (char*)d_ws;
  size_t off = 0;
  auto alloc = [&](size_t bytes) -> void* {
    void* ptr = basep + off;
    off = (off + bytes + 255) & ~(size_t)255;
    return ptr;
  };
  int*   cnt     = (int*)alloc((size_t)NN * 4);
  int*   csr_off = (int*)alloc((size_t)(NN + 1) * 4);
  float* dis     = (float*)alloc((size_t)NN * 4);
  int*   csr_src = (int*)alloc((size_t)EE * 4);
  uint2* pairs   = (uint2*)alloc((size_t)EE * 8);
  int*   perm    = (int*)alloc((size_t)NN * 4);
  int*   ghist   = (int*)alloc(256 * 4);
  int*   gcur    = (int*)alloc(256 * 4);
  int*   bexclB  = (int*)alloc(256 * 4);
  int*   hist    = (int*)alloc(NBIN * 4);
  int*   bincur  = (int*)alloc(NBIN * 4);
  float* x1s     = (float*)alloc((size_t)NN * 4);
  float* x2s     = (float*)alloc((size_t)NN * 4);
  float* pp      = (float*)alloc((size_t)NN * 4);
  float* qq      = (float*)alloc((size_t)NN * 4);
  float* uA1     = (float*)alloc((size_t)NN * 4);
  float* uA2     = (float*)alloc((size_t)NN * 4);
  float* uB1     = (float*)alloc((size_t)NN * 4);
  float* uB2     = (float*)alloc((size_t)NN * 4);
  __half* x12h   = (__half*)alloc((size_t)NN * 12 * 2);
  __half* A32    = (__half*)alloc((size_t)NN * 32 * 2);
  __half* w1h    = (__half*)alloc((size_t)128 * 32 * 2);
  __half* w2h    = (__half*)alloc((size_t)128 * 256 * 2);
  __half* x1a_h  = (__half*)alloc((size_t)NN * 128 * 2);   // region1 overlay after mm2
  __half* mean128_h = (__half*)alloc((size_t)NN * 128 * 2);
  float* region2 = (float*)alloc((size_t)NN * 72 * 4);

  // Region 1 overlay (x1a_h = 64N f32-equiv; reused after k_mm2_mfma):
  float* r1 = (float*)x1a_h;
  float*  Pa      = r1;                              // [3][N][8] = 24N (add slices 0..2)
  __half* PaTop_h = (__half*)(r1 + (size_t)NN * 24); // [N][8] fp16 prescaled
  __half* zaA     = (__half*)(r1 + (size_t)NN * 28);
  __half* zbA     = (__half*)(r1 + (size_t)NN * 32);
  __half* x2a     = (__half*)(r1 + (size_t)NN * 36);
  float*  P2      = r1 + (size_t)NN * 40;            // [4][N]; slice 3 prescaled
  // Region 2:
  float*  Pb      = region2;                              // [6][N][8] = 48N (adds 0..5)
  __half* PbTop_h = (__half*)(region2 + (size_t)NN * 48);
  __half* zaB     = (__half*)(region2 + (size_t)NN * 52);
  __half* zbB     = (__half*)(region2 + (size_t)NN * 56);
  __half* x3a     = (__half*)(region2 + (size_t)NN * 60);
  float*  P2b     = region2 + (size_t)NN * 64;            // [7][N]; slice 6 prescaled

  // ---- CSR build (bucketed) ----
  hipMemsetAsync(ghist, 0, 256 * 4, stream);
  k_bhist<<<512, 256, 0, stream>>>(ei, ghist);
  k_b196scan<<<1, 256, 0, stream>>>(ghist, gcur, bexclB, csr_off);
  k_split<<<(EE + 4095) / 4096, 256, 0, stream>>>(ei, gcur, pairs);
  k_bcount<<<NBK, 256, 0, stream>>>(pairs, bexclB, cnt, csr_off, dis);
  k_bfill<<<NBK, 256, 0, stream>>>(pairs, bexclB, csr_off, csr_src);

  // ---- degree sort ----
  hipMemsetAsync(hist, 0, NBIN * 4, stream);
  k_hist<<<(NN + 255) / 256, 256, 0, stream>>>(cnt, hist);
  k_binscan<<<1, 64, 0, stream>>>(hist, bincur);
  k_scatter<<<(NN + 255) / 256, 256, 0, stream>>>(cnt, bincur, perm);

  // ---- prep ----
  k_wcast1<<<16, 256, 0, stream>>>(s1wl, s1wr, w1h);
  k_wcast<<<128, 256, 0, stream>>>(s2wl, s2wr, w2h);
  k_pad12h<<<(NN * 12 + 255) / 256, 256, 0, stream>>>(x, x12h);
  k_prep_a32<<<(NN + 255) / 256, 256, 0, stream>>>(x, A32);

  // ---- SAGE chain ----
  k_gmean12h<<<(NN + 63) / 64, 256, 0, stream>>>(x12h, perm, csr_off, csr_src, A32);
  k_mm1_mfma<<<(NN + 127) / 128, 256, 0, stream>>>(A32, w1h, s1b, x1a_h);
  k_gather128<<<(NN + 15) / 16, 256, 0, stream>>>(x1a_h, perm, csr_off, csr_src, mean128_h);
  k_mm2_mfma<<<(NN + 127) / 128, 256, 0, stream>>>(mean128_h, x1a_h, w2h, s2b, s3wl, s3wr, pp, qq);
  k_g1_single<0><<<(NN + 63) / 64, 256, 0, stream>>>(
      pp, qq, s3b, 2, perm, csr_off, csr_src, dis, x1s);

  // ---- TAG P precompute (after mm2 frees region1) ----
  k_tagP8<4><<<(NN + 255) / 256, 256, 0, stream>>>(x, t1aw, dis, Pa, PaTop_h);
  k_tagP8<7><<<(NN + 255) / 256, 256, 0, stream>>>(x, t1bw, dis, Pb, PbTop_h);

  const size_t S8 = (size_t)NN * 8;
  // ---- D=8 hops (chain a: 3 hops; chain b: 6 hops), fp16 prescaled streams ----
  k_g8h_dual<<<(NN + 127) / 128, 256, 0, stream>>>(
      PaTop_h, Pa + 2 * S8, nullptr, 3,
      PbTop_h, Pb + 5 * S8, nullptr, 3,
      perm, csr_off, csr_src, dis, zaA, zaB);
  k_g8h_dual<<<(NN + 127) / 128, 256, 0, stream>>>(
      zaA, Pa + 1 * S8, nullptr, 3,
      zaB, Pb + 4 * S8, nullptr, 3,
      perm, csr_off, csr_src, dis, zbA, zbB);
  k_g8h_dual<<<(NN + 127) / 128, 256, 0, stream>>>(
      zbA, Pa, t1ab, 1,
      zbB, Pb + 3 * S8, nullptr, 3,
      perm, csr_off, csr_src, dis, x2a, zaB);
  k_g8h_single<<<(NN + 127) / 128, 256, 0, stream>>>(
      zaB, Pb + 2 * S8, nullptr, 3, perm, csr_off, csr_src, dis, zbB);
  k_g8h_single<<<(NN + 127) / 128, 256, 0, stream>>>(
      zbB, Pb + 1 * S8, nullptr, 3, perm, csr_off, csr_src, dis, zaB);
  k_g8h_single<<<(NN + 127) / 128, 256, 0, stream>>>(
      zaB, Pb, t1bb, 1, perm, csr_off, csr_src, dis, x3a);

  // ---- second TAG linears ----
  k_tagP1<4><<<(NN + 255) / 256, 256, 0, stream>>>(x2a, t2aw, dis, P2);
  k_tagP1<7><<<(NN + 255) / 256, 256, 0, stream>>>(x3a, t2bw, dis, P2b);

  // ---- D=1 hops (prescaled f32 streams) ----
  k_g1_dual<1><<<(NN + 63) / 64, 256, 0, stream>>>(
      P2 + 3 * (size_t)NN, P2 + 2 * (size_t)NN, nullptr, 3,
      P2b + 6 * (size_t)NN, P2b + 5 * (size_t)NN, nullptr, 3,
      perm, csr_off, csr_src, dis, uA1, uB1);
  k_g1_dual<1><<<(NN + 63) / 64, 256, 0, stream>>>(
      uA1, P2 + 1 * (size_t)NN, nullptr, 3,
      uB1, P2b + 4 * (size_t)NN, nullptr, 3,
      perm, csr_off, csr_src, dis, uA2, uB2);
  k_g1_dual<1><<<(NN + 63) / 64, 256, 0, stream>>>(
      uA2, P2, t2ab, 2,
      uB2, P2b + 3 * (size_t)NN, nullptr, 3,
      perm, csr_off, csr_src, dis, x2s, uB1);
  k_g1_single<1><<<(NN + 63) / 64, 256, 0, stream>>>(
      uB1, P2b + 2 * (size_t)NN, nullptr, 3, perm, csr_off, csr_src, dis, uB2);
  k_g1_single<1><<<(NN + 63) / 64, 256, 0, stream>>>(
      uB2, P2b + 1 * (size_t)NN, nullptr, 3, perm, csr_off, csr_src, dis, uB1);
  k_g1_final<<<(NN + 63) / 64, 256, 0, stream>>>(
      uB1, P2b, t2bb, x1s, x2s, lw, lb, perm, csr_off, csr_src, dis, out);
}